// Round 11
// baseline (669.301 us; speedup 1.0000x reference)
//
#include <hip/hip_runtime.h>
#include <cstdio>
#include <math.h>

typedef unsigned short u16;
typedef float f32x4 __attribute__((ext_vector_type(4)));
typedef __bf16 bf16x8 __attribute__((ext_vector_type(8)));
typedef u16 u16x4 __attribute__((ext_vector_type(4)));
typedef u16 u16x8 __attribute__((ext_vector_type(8)));

__device__ __forceinline__ u16 f2bf(float x) {
  unsigned u = __float_as_uint(x);
  u = (u + 0x7FFFu + ((u >> 16) & 1u)) >> 16;
  return (u16)u;
}
__device__ __forceinline__ float bf2f(u16 x) {
  return __uint_as_float(((unsigned)x) << 16);
}

__device__ __forceinline__ f32x4 mfma_bf16(bf16x8 a, bf16x8 b, f32x4 c) {
  return __builtin_amdgcn_mfma_f32_16x16x32_bf16(a, b, c, 0, 0, 0);
}

// async global->LDS, 16B per lane. LDS dest = wave-uniform base + lane*16.
__device__ __forceinline__ void gload_lds16(const void* g, void* l) {
  __builtin_amdgcn_global_load_lds(
      (const __attribute__((address_space(1))) void*)g,
      (__attribute__((address_space(3))) void*)l, 16, 0, 0);
}

// C[m,n] = scale * sum_k A[m,k] * B[n,k]   (both operands K-contiguous)
// BM=BN=256, BK=64. 512 threads = 8 waves (2M x 4N), per-wave 128x64 out.
// 4 phases per K-64 tile (r10-proven core, unchanged):
// each phase = {ds-read quadrant frags; stage 1 half-tile (2 gloads);
//   s_barrier; lgkmcnt(0)+sched_barrier(0); setprio(1); 16 MFMA; setprio(0);
//   [counted vmcnt]; s_barrier}. LDS 128KB = 2 buf x {A 32K + B' 32K}.
// Waits: end-ph1 vmcnt(2) retires B-hi'(t); end-ph4 vmcnt(2) retires
// A-lo,A-hi,B-lo'(t+1). Never vmcnt(0) mid-loop. Swizzle: rows = 128B =
// 8 x 16B slots, slot ^= row&7 via pre-swizzled global SOURCE + swizzled read.
// r11: K-range generalized to [kt0, ktN) tiles for split-K PV.
// Block-index modes:
//  PVK >= 0: PV split-K. grid (x=z, y=o-mblock, z=tbidx); tb = 7-blockIdx.z
//    (descending work -> LPT scheduling: biggest blocks dispatch first).
//    ntFull = (tb+1)*4 K-tiles (causal bound); PVK=0: [0, nA) plain store;
//    PVK=1: [nA, ntFull) with C += epilogue (stream-ordered after PVK=0).
//  TRI: compact causal grid: gridDim.x == 36 live tiles of 8x8 triangular
//    tiling (bx <= by), z = f/36. Equal-work tiles; SWZ keeps XCD locality.
//  SWZ: chunked XCD swizzle on flattened id (identity unless nwg%8==0).
template <bool BF16OUT, bool SWZ, bool TRI, int PVK>
__global__ __launch_bounds__(512, 2) void gemm_bt(
    const u16* __restrict__ A, const u16* __restrict__ B, void* __restrict__ Cv,
    int K, int lda, int ldb, int ldc,
    long long sAz, long long sBz, long long sCz, float scale)
{
  int bx, by, z, kt0, ktN;
  if (PVK >= 0) {
    const int tb = 7 - (int)blockIdx.z;   // big tiles first -> LPT balance
    bx = tb; by = (int)blockIdx.y; z = (int)blockIdx.x;
    const int ntFull = (tb + 1) * 4;      // == (tb*256+256)/64, causal kEnd
    const int nA = (ntFull + 1) >> 1;
    kt0 = (PVK == 0) ? 0 : nA;
    ktN = (PVK == 0) ? nA : ntFull;
  } else {
    const int gx = gridDim.x, gy = gridDim.y;
    const int nwg = gx * gy * gridDim.z;
    int f = blockIdx.x + gx * (blockIdx.y + gy * blockIdx.z);
    if (SWZ && (nwg & 7) == 0) f = (f & 7) * (nwg >> 3) + (f >> 3);
    if (TRI) {
      const int j = f % gx;  // gx == 36
      z = f / gx;
      int r = (int)((sqrtf(8.f * j + 1.f) - 1.f) * 0.5f);
      while (r * (r + 1) / 2 > j) --r;
      while ((r + 1) * (r + 2) / 2 <= j) ++r;
      by = r;
      bx = j - r * (r + 1) / 2;
    } else {
      bx = f % gx;
      const int rest = f / gx;
      by = rest % gy;
      z = rest / gy;
    }
    kt0 = 0; ktN = K >> 6;
  }

  const int n0 = bx * 256;
  const int m0 = by * 256;
  A += (long long)z * sAz;
  B += (long long)z * sBz;

  const int tid = threadIdx.x;
  const int wave = tid >> 6, lane = tid & 63;
  const int wr = wave >> 2, wc = wave & 3;  // 2M x 4N wave grid

  // per buffer (32768 u16): A [256][64] at 0..16383; B' halves at 16384 +
  // half*8192 + r'[0..127]*64.
  __shared__ u16 lds[2][32768];

  f32x4 acc[8][4] = {};

  const int nt = ktN - kt0;  // >= 2 for all our launches

  // ---- staging: one gload call = 512 lanes x 16B = 64 rows of 128B.
  // lane l of wave w: row-in-call = w*8 + (l>>3), phys slot = l&7.
  // pre-swizzled source: logical slot = phys ^ (row&7); row&7 == (l>>3)&7.
  const int sOff = ((lane & 7) ^ ((lane >> 3) & 7)) * 8;  // elem offset in row
  const int r0 = wave * 8 + (lane >> 3);                  // row within call
  const u16* gA0 = A + (long long)(m0 + r0) * lda + sOff; // + c*64*lda + k
  // B call c (c0,1 = B-lo', c2,3 = B-hi'): r' = (c&1)*64 + r0;
  // actual row = (r'>>5)*64 + (c>>1)*32 + (r'&31). (r'&7 == r0&7 -> sOff ok)

  // ---- read: logical (row, slot s) at phys slot s^(row&7); frag rows have
  // row&7 == frow&7 (all bases = 0 mod 8... wc*32,(n&1)*16,m*16,wr*128).
  const int frow = lane & 15, g = lane >> 4, swz = frow & 7;

#define AOFF(m, kk) ((wr * 128 + (m) * 16 + frow) * 64 + ((((kk) * 4 + g)) ^ swz) * 8)
#define BOFF(n, kk) (16384 + ((n) >> 1) * 8192 + (wc * 32 + ((n) & 1) * 16 + frow) * 64 + (((kk) * 4 + g) ^ swz) * 8)

#define STAGE_A(T, BUF, H)                                                     \
  {                                                                            \
    const long long kc = (long long)(T) * 64;                                  \
    _Pragma("unroll")                                                          \
    for (int c = (H) * 2; c < (H) * 2 + 2; ++c)                                \
      gload_lds16(gA0 + (long long)(c * 64) * lda + kc,                        \
                  &lds[BUF][c * 4096 + wave * 512]);                           \
  }
#define STAGE_B(T, BUF, H)                                                     \
  {                                                                            \
    const long long kc = (long long)(T) * 64;                                  \
    _Pragma("unroll")                                                          \
    for (int c = (H) * 2; c < (H) * 2 + 2; ++c) {                              \
      const int rp = (c & 1) * 64 + r0;                                        \
      const int row = (rp >> 5) * 64 + (c >> 1) * 32 + (rp & 31);              \
      gload_lds16(B + (long long)(n0 + row) * ldb + sOff + kc,                 \
                  &lds[BUF][16384 + c * 4096 + wave * 512]);                   \
    }                                                                          \
  }

  bf16x8 pA[8], pB[4];
#define READ_A(mb)                                                             \
  _Pragma("unroll")                                                            \
  for (int i = 0; i < 4; ++i) {                                                \
    pA[i * 2 + 0] = *(const bf16x8*)(bb + AOFF((mb) + i, 0));                  \
    pA[i * 2 + 1] = *(const bf16x8*)(bb + AOFF((mb) + i, 1));                  \
  }
#define READ_B(nb)                                                             \
  _Pragma("unroll")                                                            \
  for (int i = 0; i < 2; ++i) {                                                \
    pB[i * 2 + 0] = *(const bf16x8*)(bb + BOFF((nb) + i, 0));                  \
    pB[i * 2 + 1] = *(const bf16x8*)(bb + BOFF((nb) + i, 1));                  \
  }
#define MFMA16(mb, nb)                                                         \
  _Pragma("unroll")                                                            \
  for (int i = 0; i < 4; ++i)                                                  \
    _Pragma("unroll")                                                          \
    for (int j = 0; j < 2; ++j) {                                              \
      acc[(mb) + i][(nb) + j] =                                                \
          mfma_bf16(pA[i * 2 + 0], pB[j * 2 + 0], acc[(mb) + i][(nb) + j]);    \
      acc[(mb) + i][(nb) + j] =                                                \
          mfma_bf16(pA[i * 2 + 1], pB[j * 2 + 1], acc[(mb) + i][(nb) + j]);    \
    }

#define BAR()  __builtin_amdgcn_s_barrier()
#define LGKM0()                                                                \
  asm volatile("s_waitcnt lgkmcnt(0)" ::: "memory");                           \
  __builtin_amdgcn_sched_barrier(0)
#define VM(N) asm volatile("s_waitcnt vmcnt(" #N ")" ::: "memory")

  // ---- prologue: stage tile kt0 (A-lo, A-hi, B-lo', B-hi' = 8 loads FIFO);
  // vmcnt(2) retires all but B-hi' (first read in ph2, revalidated end-ph1).
  STAGE_A(kt0, 0, 0) STAGE_A(kt0, 0, 1) STAGE_B(kt0, 0, 0) STAGE_B(kt0, 0, 1)
  VM(2);
  BAR();

  for (int i2 = 0; i2 < nt; ++i2) {
    const u16* bb = &lds[i2 & 1][0];
    const int nxb = (i2 + 1) & 1;
    const bool pf = (i2 + 1 < nt);
    const int tn = kt0 + i2 + 1;

    // ph1: read A m0-3 + B n0-1; stage A-lo(t+1); MFMA m0-3 x n0-1
    READ_A(0) READ_B(0)
    if (pf) STAGE_A(tn, nxb, 0)
    BAR(); LGKM0();
    __builtin_amdgcn_s_setprio(1); MFMA16(0, 0); __builtin_amdgcn_s_setprio(0);
    if (pf) VM(2); else VM(0);   // retire B-hi'(t) before ph2 reads it
    BAR();

    // ph2: read B n2-3 (A regs reused); stage A-hi(t+1); MFMA m0-3 x n2-3
    READ_B(2)
    if (pf) STAGE_A(tn, nxb, 1)
    BAR(); LGKM0();
    __builtin_amdgcn_s_setprio(1); MFMA16(0, 2); __builtin_amdgcn_s_setprio(0);
    BAR();

    // ph3: read A m4-7 (B regs reused); stage B-lo'(t+1); MFMA m4-7 x n2-3
    READ_A(4)
    if (pf) STAGE_B(tn, nxb, 0)
    BAR(); LGKM0();
    __builtin_amdgcn_s_setprio(1); MFMA16(4, 2); __builtin_amdgcn_s_setprio(0);
    BAR();

    // ph4: read B n0-1; stage B-hi'(t+1); MFMA m4-7 x n0-1
    READ_B(0)
    if (pf) STAGE_B(tn, nxb, 1)
    BAR(); LGKM0();
    __builtin_amdgcn_s_setprio(1); MFMA16(4, 0); __builtin_amdgcn_s_setprio(0);
    if (pf) VM(2); else VM(0);   // retire A-lo,A-hi,B-lo'(t+1) for ph1
    BAR();
  }
#undef STAGE_A
#undef STAGE_B
#undef READ_A
#undef READ_B
#undef MFMA16
#undef AOFF
#undef BOFF
#undef BAR
#undef LGKM0
#undef VM

  // C/D layout: col = lane&15, row = (lane>>4)*4 + r  [m89-verified]
  const int crow0 = m0 + wr * 128 + (lane >> 4) * 4;
  const int ccol0 = n0 + wc * 64 + (lane & 15);
  if (BF16OUT) {
    u16* C = (u16*)Cv + (long long)z * sCz;
#pragma unroll
    for (int m = 0; m < 8; ++m)
#pragma unroll
      for (int n = 0; n < 4; ++n)
#pragma unroll
        for (int r = 0; r < 4; ++r)
          C[(long long)(crow0 + m * 16 + r) * ldc + ccol0 + n * 16] = f2bf(acc[m][n][r] * scale);
  } else {
    float* C = (float*)Cv + (long long)z * sCz;
    if (PVK == 1) {
      // second K-half: accumulate onto PV-A's output (stream-ordered)
#pragma unroll
      for (int m = 0; m < 8; ++m)
#pragma unroll
        for (int n = 0; n < 4; ++n)
#pragma unroll
          for (int r = 0; r < 4; ++r) {
            const long long off = (long long)(crow0 + m * 16 + r) * ldc + ccol0 + n * 16;
            C[off] += acc[m][n][r] * scale;
          }
    } else {
#pragma unroll
      for (int m = 0; m < 8; ++m)
#pragma unroll
        for (int n = 0; n < 4; ++n)
#pragma unroll
          for (int r = 0; r < 4; ++r)
            C[(long long)(crow0 + m * 16 + r) * ldc + ccol0 + n * 16] = acc[m][n][r] * scale;
    }
  }
}

// (b, i, s) fp32  ->  (b, s, i) bf16 ; one 64x64 tile per block, block (64,4)
__global__ __launch_bounds__(256) void conv_transpose(const float* __restrict__ src, u16* __restrict__ dst)
{
  const int b = blockIdx.z;
  const float* s = src + (long long)b * 1024 * 2048;
  u16* d = dst + (long long)b * 2048 * 1024;
  const int s0 = blockIdx.x * 64, i0 = blockIdx.y * 64;
  const int tx = threadIdx.x, ty = threadIdx.y;
  __shared__ float tile[64][65];
#pragma unroll
  for (int r = 0; r < 16; ++r)
    tile[r * 4 + ty][tx] = s[(long long)(i0 + r * 4 + ty) * 2048 + s0 + tx];
  __syncthreads();
#pragma unroll
  for (int r = 0; r < 16; ++r)
    d[(long long)(s0 + r * 4 + ty) * 1024 + i0 + tx] = f2bf(tile[tx][r * 4 + ty]);
}

__global__ __launch_bounds__(256) void conv_weights(
    const float* __restrict__ a, const float* __restrict__ b, const float* __restrict__ c,
    u16* __restrict__ oa, u16* __restrict__ ob, u16* __restrict__ oc)
{
  const int which = blockIdx.y;
  const float* s = which == 0 ? a : which == 1 ? b : c;
  u16* d = which == 0 ? oa : which == 1 ? ob : oc;
  const int idx = (blockIdx.x * 256 + threadIdx.x) * 4;
  f32x4 v = *(const f32x4*)(s + idx);
  u16x4 o;
#pragma unroll
  for (int j = 0; j < 4; ++j) o[j] = f2bf(v[j]);
  *(u16x4*)(d + idx) = o;
}

// Row t of S'[t,s] (bf16): mask by index (s<=t), max, sum-exp, write P bf16
// IN PLACE (each thread reads only its own 8 elems before writing them).
// One row per block; 256 threads x 8 elems = 2048. Zeros masked region
// (exp(-1e30-m)=0) so PV may read P[t, s in (t, tileEnd)] safely.
__global__ __launch_bounds__(256) void col_softmax(const u16* __restrict__ S, u16* __restrict__ P)
{
  const int t = blockIdx.x;
  const long long rowOff = ((long long)blockIdx.y * 2048 + t) * 2048;
  const u16* row = S + rowOff;
  u16* prow = P + rowOff;
  const int tid = threadIdx.x;
  const int i0 = tid * 8;

  u16x8 a = *(const u16x8*)(row + i0);
  float v[8];
#pragma unroll
  for (int j = 0; j < 8; ++j)
    v[j] = (i0 + j <= t) ? bf2f(a[j]) : -1e30f;  // unwritten/masked discarded by index

  float m = v[0];
#pragma unroll
  for (int j = 1; j < 8; ++j) m = fmaxf(m, v[j]);
#pragma unroll
  for (int off = 32; off; off >>= 1) m = fmaxf(m, __shfl_xor(m, off));
  __shared__ float red[4];
  __shared__ float red2[4];
  if ((tid & 63) == 0) red[tid >> 6] = m;
  __syncthreads();
  m = fmaxf(fmaxf(red[0], red[1]), fmaxf(red[2], red[3]));

  float e[8]; float ssum = 0.f;
#pragma unroll
  for (int j = 0; j < 8; ++j) { e[j] = __expf(v[j] - m); ssum += e[j]; }
#pragma unroll
  for (int off = 32; off; off >>= 1) ssum += __shfl_xor(ssum, off);
  if ((tid & 63) == 0) red2[tid >> 6] = ssum;
  __syncthreads();
  ssum = red2[0] + red2[1] + red2[2] + red2[3];
  const float inv = 1.0f / ssum;
  u16x8 o;
#pragma unroll
  for (int j = 0; j < 8; ++j) o[j] = f2bf(e[j] * inv);
  *(u16x8*)(prow + i0) = o;
}

extern "C" void kernel_launch(void* const* d_in, const int* in_sizes, int n_in,
                              void* d_out, int out_size, void* d_ws, size_t ws_size,
                              hipStream_t stream)
{
  const float* Q  = (const float*)d_in[0];
  const float* K  = (const float*)d_in[1];
  const float* V  = (const float*)d_in[2];
  const float* WQ = (const float*)d_in[3];
  const float* WK = (const float*)d_in[4];
  const float* WV = (const float*)d_in[5];
  float* out = (float*)d_out;

  const size_t MB = 1ull << 20;
  char* w = (char*)d_ws;
  if (ws_size < 326 * MB) {
    fprintf(stderr, "kernel_launch: workspace too small (%zu B, need >= %zu B)\n",
            ws_size, (size_t)(326 * MB));
    return;
  }

  // ws layout (MB): [0,6) weights bf16 | [6,70) Qd_t | [70,134) Kd_t |
  // [134,198) Vd | [198,326): transposed-input buffer (64MB) during proj,
  // then S bf16 for ALL 16 batches (128MB; softmax is in-place -> no P).
  u16* wq    = (u16*)(w + 0 * MB);
  u16* wk    = (u16*)(w + 2 * MB);
  u16* wv    = (u16*)(w + 4 * MB);
  u16* qdt   = (u16*)(w + 6 * MB);
  u16* kdt   = (u16*)(w + 70 * MB);
  u16* vd    = (u16*)(w + 134 * MB);
  u16* trans = (u16*)(w + 198 * MB);
  u16* S     = (u16*)(w + 198 * MB);

  conv_weights<<<dim3(1024, 3), 256, 0, stream>>>(WQ, WK, WV, wq, wk, wv);

  // Projections. Qd_t/Kd_t stored (b, seq, o) = one (32768 x 1024) GEMM each;
  // Vd stored (b, o, seq), per-batch z.
  conv_transpose<<<dim3(32, 16, 16), dim3(64, 4), 0, stream>>>(Q, trans);
  gemm_bt<true, true, false, -1><<<dim3(4, 128, 1), 512, 0, stream>>>(
      trans, wq, qdt, 1024, 1024, 1024, 1024, 0, 0, 0, 1.0f);
  conv_transpose<<<dim3(32, 16, 16), dim3(64, 4), 0, stream>>>(K, trans);
  gemm_bt<true, true, false, -1><<<dim3(4, 128, 1), 512, 0, stream>>>(
      trans, wk, kdt, 1024, 1024, 1024, 1024, 0, 0, 0, 1.0f);
  conv_transpose<<<dim3(32, 16, 16), dim3(64, 4), 0, stream>>>(V, trans);
  gemm_bt<true, true, false, -1><<<dim3(8, 4, 16), 512, 0, stream>>>(
      wv, trans, vd, 1024, 1024, 1024, 2048,
      0, (long long)2048 * 1024, (long long)1024 * 2048, 1.0f);

  // Attention, all 16 batches per dispatch:
  //  S'[t,s] = Kd_t[t,:]·Qd_t[s,:]/32 — compact triangular grid, 36 tiles/z
  //  x 16 z = 576 blocks (uniform work), chunked XCD swizzle.
  gemm_bt<true, true, true, -1><<<dim3(36, 1, 16), 512, 0, stream>>>(
      kdt, qdt, S, 1024, 1024, 1024, 2048,
      (long long)2048 * 1024, (long long)2048 * 1024, (long long)2048 * 2048, 0.03125f);
  //  row-softmax over s (masked by index), IN PLACE (P == S buffer)
  col_softmax<<<dim3(2048, 16), 256, 0, stream>>>(S, S);
  //  out[o,t] = sum_s Vd[o,s] P[t,s] — split-K: PV-A K-tiles [0,nA) stores,
  //  PV-B [nA,ntFull) accumulates (+=). tb decoded descending -> LPT balance
  //  (r10 lesson: monolithic PV is bound by the 32-tile t-block = 91 us).
  gemm_bt<false, false, false, 0><<<dim3(16, 4, 8), 512, 0, stream>>>(
      vd, S, out, 2048, 2048, 2048, 2048,
      (long long)1024 * 2048, (long long)2048 * 2048, (long long)1024 * 2048, 1.0f);
  gemm_bt<false, false, false, 1><<<dim3(16, 4, 8), 512, 0, stream>>>(
      vd, S, out, 2048, 2048, 2048, 2048,
      (long long)1024 * 2048, (long long)2048 * 2048, (long long)1024 * 2048, 1.0f);
}

// Round 12
// 566.417 us; speedup vs baseline: 1.1816x; 1.1816x over previous
//
#include <hip/hip_runtime.h>
#include <cstdio>
#include <math.h>

typedef unsigned short u16;
typedef float f32x4 __attribute__((ext_vector_type(4)));
typedef __bf16 bf16x8 __attribute__((ext_vector_type(8)));
typedef u16 u16x4 __attribute__((ext_vector_type(4)));
typedef u16 u16x8 __attribute__((ext_vector_type(8)));

__device__ __forceinline__ u16 f2bf(float x) {
  unsigned u = __float_as_uint(x);
  u = (u + 0x7FFFu + ((u >> 16) & 1u)) >> 16;
  return (u16)u;
}
__device__ __forceinline__ float bf2f(u16 x) {
  return __uint_as_float(((unsigned)x) << 16);
}

__device__ __forceinline__ f32x4 mfma_bf16(bf16x8 a, bf16x8 b, f32x4 c) {
  return __builtin_amdgcn_mfma_f32_16x16x32_bf16(a, b, c, 0, 0, 0);
}

// async global->LDS, 16B per lane. LDS dest = wave-uniform base + lane*16.
__device__ __forceinline__ void gload_lds16(const void* g, void* l) {
  __builtin_amdgcn_global_load_lds(
      (const __attribute__((address_space(1))) void*)g,
      (__attribute__((address_space(3))) void*)l, 16, 0, 0);
}

// C[m,n] = scale * sum_k A[m,k] * B[n,k].  BM=BN=256, BK=64, 512 thr = 8 waves
// (2M x 4N), per-wave 128x64 out. LDS 128KB = 2 buf x {A 32K + B' 32K}.
//
// TMODE=0 (bf16 A,B both K-contig): r10-proven counted-vmcnt 4-phase loop.
// TMODE=1/2 (r12): operand A/B fused TRANSPOSE+CVT from fp32 k-major source
//  Tf (layout [k][s], stride 2048) — replaces the separate conv_transpose
//  pass. Per tile per wave: 8 coalesced dwordx4 (k-row w*8+r, s=lane*4..+3),
//  register transpose, 32 f2bf, 4 ds_write_b128. Loop: per-tile vmcnt(0)
//  at end-ph4 (issued a full tile earlier -> no stall), lgkmcnt(0) before
//  boundary barrier for cross-wave write visibility.
// Swizzle: gload-staged regions keep slot ^= row&7 (proven, 0 conflicts).
//  Reg-WRITTEN regions need f(row) = (row&7)^((row>>2)&7): uniform over
//  row-bits 0-2 (reads: 2 lanes/slot) AND bits 2-7 (writes: rows=4*lane+j
//  -> all 8 slots across lanes). Read offsets match per-operand formula.
// Block-index modes:
//  PVLPT: grid (x=z, y=o-mblock, z=tbidx), bx = 7-blockIdx.z (descending ->
//    LPT: first 256 blocks are the big t-blocks; queue refills descending).
//  TRI: compact causal grid, gridDim.x == 36 tiles of 8x8 triangular tiling.
//  SWZ: chunked XCD swizzle on flattened id (identity unless nwg%8==0).
template <bool BF16OUT, bool SWZ, bool TRI, bool KLIMIT, bool PVLPT, int TMODE>
__global__ __launch_bounds__(512, 2) void gemm_bt(
    const u16* __restrict__ A, const u16* __restrict__ B,
    const float* __restrict__ Tf, void* __restrict__ Cv,
    int K, int lda, int ldb, int ldc,
    long long sAz, long long sBz, long long sCz, float scale)
{
  int bx, by, z;
  if (PVLPT) {
    z = (int)blockIdx.x; by = (int)blockIdx.y; bx = 7 - (int)blockIdx.z;
  } else {
    const int gx = gridDim.x, gy = gridDim.y;
    const int nwg = gx * gy * gridDim.z;
    int f = blockIdx.x + gx * (blockIdx.y + gy * blockIdx.z);
    if (SWZ && (nwg & 7) == 0) f = (f & 7) * (nwg >> 3) + (f >> 3);
    if (TRI) {
      const int j = f % gx;  // gx == 36
      z = f / gx;
      int r = (int)((sqrtf(8.f * j + 1.f) - 1.f) * 0.5f);
      while (r * (r + 1) / 2 > j) --r;
      while ((r + 1) * (r + 2) / 2 <= j) ++r;
      by = r;
      bx = j - r * (r + 1) / 2;
    } else {
      bx = f % gx;
      const int rest = f / gx;
      by = rest % gy;
      z = rest / gy;
    }
  }

  const int n0 = bx * 256;
  const int m0 = by * 256;
  A += (long long)z * sAz;
  B += (long long)z * sBz;

  const int tid = threadIdx.x;
  const int wave = tid >> 6, lane = tid & 63;
  const int wr = wave >> 2, wc = wave & 3;  // 2M x 4N wave grid

  // per buffer (32768 u16): A [256][64] at 0..16383; B' halves at 16384 +
  // half*8192 + r'[0..127]*64.
  __shared__ u16 lds[2][32768];

  f32x4 acc[8][4] = {};

  int kEnd = K;
  if (KLIMIT || PVLPT) { int ke = n0 + 256; kEnd = ke < K ? ke : K; }
  const int nt = kEnd >> 6;

  // ---- gload staging (old swizzle slot^=row&7, pre-swizzled source):
  const int sOff = ((lane & 7) ^ ((lane >> 3) & 7)) * 8;  // elem offset in row
  const int r0 = wave * 8 + (lane >> 3);                  // row within call
  const u16* gA0 = A + (long long)(m0 + r0) * lda + sOff;

  // ---- transpose source (fp32, [k][2048])
  const float* Tsrc = nullptr;
  if (TMODE == 1) Tsrc = Tf + ((long long)(m0 >> 11) * 1024) * 2048 + (m0 & 2047);
  else if (TMODE == 2) Tsrc = Tf + ((long long)z * 1024) * 2048 + n0;
  const int tcol = lane * 4;
  f32x4 tv[8];

  // ---- read offsets. frag rows: A: wr*128+m*16+frow; B': wc*32+(n&1)*16+frow.
  const int frow = lane & 15, g = lane >> 4;
  const int swzA0 = (TMODE == 1) ? ((frow & 7) ^ (frow >> 2)) : (frow & 7);
  const int swzA1 = (TMODE == 1) ? ((frow & 7) ^ (4 + (frow >> 2))) : (frow & 7);
  const int swzB0 = (TMODE == 2) ? ((frow & 7) ^ (frow >> 2)) : (frow & 7);
  const int swzB1 = (TMODE == 2) ? ((frow & 7) ^ (4 + (frow >> 2))) : (frow & 7);

#define AOFF(m, kk) ((wr * 128 + (m) * 16 + frow) * 64 + \
                     (((kk) * 4 + g) ^ (((m) & 1) ? swzA1 : swzA0)) * 8)
#define BOFF(n, kk) (16384 + ((n) >> 1) * 8192 + (wc * 32 + ((n) & 1) * 16 + frow) * 64 + \
                     (((kk) * 4 + g) ^ (((n) & 1) ? swzB1 : swzB0)) * 8)

#define STAGE_A(T, BUF, H)                                                     \
  {                                                                            \
    const long long kc = (long long)(T) * 64;                                  \
    _Pragma("unroll")                                                          \
    for (int c = (H) * 2; c < (H) * 2 + 2; ++c)                                \
      gload_lds16(gA0 + (long long)(c * 64) * lda + kc,                        \
                  &lds[BUF][c * 4096 + wave * 512]);                           \
  }
#define STAGE_B(T, BUF, H)                                                     \
  {                                                                            \
    const long long kc = (long long)(T) * 64;                                  \
    _Pragma("unroll")                                                          \
    for (int c = (H) * 2; c < (H) * 2 + 2; ++c) {                              \
      const int rp = (c & 1) * 64 + r0;                                        \
      const int row = (rp >> 5) * 64 + (c >> 1) * 32 + (rp & 31);              \
      gload_lds16(B + (long long)(n0 + row) * ldb + sOff + kc,                 \
                  &lds[BUF][16384 + c * 4096 + wave * 512]);                   \
    }                                                                          \
  }
// issue 8 fp32 rows of tile T (k = T*64 + wave*8 + r)
#define TLOAD(T)                                                               \
  _Pragma("unroll")                                                            \
  for (int r = 0; r < 8; ++r)                                                  \
    tv[r] = *(const f32x4*)(Tsrc + (long long)((T) * 64 + wave * 8 + r) * 2048 + tcol);
// cvt + transpose-in-regs + 4 x ds_write_b128 into buf BUF
#define TCVT(BUF)                                                              \
  _Pragma("unroll")                                                            \
  for (int j = 0; j < 4; ++j) {                                                \
    const int rw = (lane << 2) + j;                                            \
    u16x8 hv;                                                                  \
    _Pragma("unroll")                                                          \
    for (int r = 0; r < 8; ++r) hv[r] = f2bf(tv[r][j]);                        \
    int ad;                                                                    \
    if (TMODE == 1) {                                                          \
      ad = rw * 64 + ((wave ^ ((rw & 7) ^ ((rw >> 2) & 7))) * 8);              \
    } else {                                                                   \
      const int h = (rw >> 5) & 1, rp = (rw >> 6) * 32 + (rw & 31);            \
      ad = 16384 + h * 8192 + rp * 64 +                                        \
           ((wave ^ ((rp & 7) ^ ((rp >> 2) & 7))) * 8);                        \
    }                                                                          \
    *(u16x8*)(&lds[BUF][ad]) = hv;                                             \
  }

  bf16x8 pA[8], pB[4];
#define READ_A(mb)                                                             \
  _Pragma("unroll")                                                            \
  for (int i = 0; i < 4; ++i) {                                                \
    pA[i * 2 + 0] = *(const bf16x8*)(bb + AOFF((mb) + i, 0));                  \
    pA[i * 2 + 1] = *(const bf16x8*)(bb + AOFF((mb) + i, 1));                  \
  }
#define READ_B(nb)                                                             \
  _Pragma("unroll")                                                            \
  for (int i = 0; i < 2; ++i) {                                                \
    pB[i * 2 + 0] = *(const bf16x8*)(bb + BOFF((nb) + i, 0));                  \
    pB[i * 2 + 1] = *(const bf16x8*)(bb + BOFF((nb) + i, 1));                  \
  }
#define MFMA16(mb, nb)                                                         \
  _Pragma("unroll")                                                            \
  for (int i = 0; i < 4; ++i)                                                  \
    _Pragma("unroll")                                                          \
    for (int j = 0; j < 2; ++j) {                                              \
      acc[(mb) + i][(nb) + j] =                                                \
          mfma_bf16(pA[i * 2 + 0], pB[j * 2 + 0], acc[(mb) + i][(nb) + j]);    \
      acc[(mb) + i][(nb) + j] =                                                \
          mfma_bf16(pA[i * 2 + 1], pB[j * 2 + 1], acc[(mb) + i][(nb) + j]);    \
    }

#define BAR()  __builtin_amdgcn_s_barrier()
#define LGKM0()                                                                \
  asm volatile("s_waitcnt lgkmcnt(0)" ::: "memory");                           \
  __builtin_amdgcn_sched_barrier(0)
#define VM(N) asm volatile("s_waitcnt vmcnt(" #N ")" ::: "memory")

  if constexpr (TMODE == 0) {
    // ---- r10-proven counted-vmcnt loop (bf16 operands, gload both) ----
    STAGE_A(0, 0, 0) STAGE_A(0, 0, 1) STAGE_B(0, 0, 0) STAGE_B(0, 0, 1)
    VM(2);
    BAR();
    for (int t = 0; t < nt; ++t) {
      const u16* bb = &lds[t & 1][0];
      const int nxb = (t + 1) & 1;
      const bool pf = (t + 1 < nt);

      READ_A(0) READ_B(0)
      if (pf) STAGE_A(t + 1, nxb, 0)
      BAR(); LGKM0();
      __builtin_amdgcn_s_setprio(1); MFMA16(0, 0); __builtin_amdgcn_s_setprio(0);
      if (pf) VM(2); else VM(0);
      BAR();

      READ_B(2)
      if (pf) STAGE_A(t + 1, nxb, 1)
      BAR(); LGKM0();
      __builtin_amdgcn_s_setprio(1); MFMA16(0, 2); __builtin_amdgcn_s_setprio(0);
      BAR();

      READ_A(4)
      if (pf) STAGE_B(t + 1, nxb, 0)
      BAR(); LGKM0();
      __builtin_amdgcn_s_setprio(1); MFMA16(4, 2); __builtin_amdgcn_s_setprio(0);
      BAR();

      READ_B(0)
      if (pf) STAGE_B(t + 1, nxb, 1)
      BAR(); LGKM0();
      __builtin_amdgcn_s_setprio(1); MFMA16(4, 0); __builtin_amdgcn_s_setprio(0);
      if (pf) VM(2); else VM(0);
      BAR();
    }
  } else {
    // ---- fused-transpose loop: per-tile vmcnt(0), writes visible via lgkm ----
    TLOAD(0)
    if (TMODE == 1) { STAGE_B(0, 0, 0) STAGE_B(0, 0, 1) }
    else            { STAGE_A(0, 0, 0) STAGE_A(0, 0, 1) }
    VM(0);
    TCVT(0)
    asm volatile("s_waitcnt lgkmcnt(0)" ::: "memory");
    BAR();
    for (int t = 0; t < nt; ++t) {
      const u16* bb = &lds[t & 1][0];
      const int nxb = (t + 1) & 1;
      const bool pf = (t + 1 < nt);

      if (pf) {
        TLOAD(t + 1)
        if (TMODE == 1) { STAGE_B(t + 1, nxb, 0) STAGE_B(t + 1, nxb, 1) }
        else            { STAGE_A(t + 1, nxb, 0) STAGE_A(t + 1, nxb, 1) }
      }

      READ_A(0) READ_B(0)
      BAR(); LGKM0();
      __builtin_amdgcn_s_setprio(1); MFMA16(0, 0); __builtin_amdgcn_s_setprio(0);
      BAR();

      READ_B(2)
      BAR(); LGKM0();
      __builtin_amdgcn_s_setprio(1); MFMA16(0, 2); __builtin_amdgcn_s_setprio(0);
      BAR();

      READ_A(4)
      BAR(); LGKM0();
      __builtin_amdgcn_s_setprio(1); MFMA16(4, 2); __builtin_amdgcn_s_setprio(0);
      BAR();

      READ_B(0)
      BAR(); LGKM0();
      __builtin_amdgcn_s_setprio(1); MFMA16(4, 0); __builtin_amdgcn_s_setprio(0);
      if (pf) {
        VM(0);      // dwordx4(t+1) regs ready + DMA(t+1) in LDS (issued 1 tile ago)
        TCVT(nxb)   // write transposed operand (t+1) into buf^1
      } else {
        VM(0);
      }
      asm volatile("s_waitcnt lgkmcnt(0)" ::: "memory");  // writes visible
      BAR();
    }
  }
#undef STAGE_A
#undef STAGE_B
#undef TLOAD
#undef TCVT
#undef READ_A
#undef READ_B
#undef MFMA16
#undef AOFF
#undef BOFF
#undef BAR
#undef LGKM0
#undef VM

  // C/D layout: col = lane&15, row = (lane>>4)*4 + r  [m89-verified]
  const int crow0 = m0 + wr * 128 + (lane >> 4) * 4;
  const int ccol0 = n0 + wc * 64 + (lane & 15);
  if (BF16OUT) {
    u16* C = (u16*)Cv + (long long)z * sCz;
#pragma unroll
    for (int m = 0; m < 8; ++m)
#pragma unroll
      for (int n = 0; n < 4; ++n)
#pragma unroll
        for (int r = 0; r < 4; ++r)
          C[(long long)(crow0 + m * 16 + r) * ldc + ccol0 + n * 16] = f2bf(acc[m][n][r] * scale);
  } else {
    float* C = (float*)Cv + (long long)z * sCz;
#pragma unroll
    for (int m = 0; m < 8; ++m)
#pragma unroll
      for (int n = 0; n < 4; ++n)
#pragma unroll
        for (int r = 0; r < 4; ++r)
          C[(long long)(crow0 + m * 16 + r) * ldc + ccol0 + n * 16] = acc[m][n][r] * scale;
  }
}

__global__ __launch_bounds__(256) void conv_weights(
    const float* __restrict__ a, const float* __restrict__ b, const float* __restrict__ c,
    u16* __restrict__ oa, u16* __restrict__ ob, u16* __restrict__ oc)
{
  const int which = blockIdx.y;
  const float* s = which == 0 ? a : which == 1 ? b : c;
  u16* d = which == 0 ? oa : which == 1 ? ob : oc;
  const int idx = (blockIdx.x * 256 + threadIdx.x) * 4;
  f32x4 v = *(const f32x4*)(s + idx);
  u16x4 o;
#pragma unroll
  for (int j = 0; j < 4; ++j) o[j] = f2bf(v[j]);
  *(u16x4*)(d + idx) = o;
}

// Row t of S'[t,s] (bf16): mask by index (s<=t), max, sum-exp, write P bf16
// IN PLACE (each thread reads only its own 8 elems before writing them).
__global__ __launch_bounds__(256) void col_softmax(const u16* __restrict__ S, u16* __restrict__ P)
{
  const int t = blockIdx.x;
  const long long rowOff = ((long long)blockIdx.y * 2048 + t) * 2048;
  const u16* row = S + rowOff;
  u16* prow = P + rowOff;
  const int tid = threadIdx.x;
  const int i0 = tid * 8;

  u16x8 a = *(const u16x8*)(row + i0);
  float v[8];
#pragma unroll
  for (int j = 0; j < 8; ++j)
    v[j] = (i0 + j <= t) ? bf2f(a[j]) : -1e30f;  // unwritten/masked discarded by index

  float m = v[0];
#pragma unroll
  for (int j = 1; j < 8; ++j) m = fmaxf(m, v[j]);
#pragma unroll
  for (int off = 32; off; off >>= 1) m = fmaxf(m, __shfl_xor(m, off));
  __shared__ float red[4];
  __shared__ float red2[4];
  if ((tid & 63) == 0) red[tid >> 6] = m;
  __syncthreads();
  m = fmaxf(fmaxf(red[0], red[1]), fmaxf(red[2], red[3]));

  float e[8]; float ssum = 0.f;
#pragma unroll
  for (int j = 0; j < 8; ++j) { e[j] = __expf(v[j] - m); ssum += e[j]; }
#pragma unroll
  for (int off = 32; off; off >>= 1) ssum += __shfl_xor(ssum, off);
  if ((tid & 63) == 0) red2[tid >> 6] = ssum;
  __syncthreads();
  ssum = red2[0] + red2[1] + red2[2] + red2[3];
  const float inv = 1.0f / ssum;
  u16x8 o;
#pragma unroll
  for (int j = 0; j < 8; ++j) o[j] = f2bf(e[j] * inv);
  *(u16x8*)(prow + i0) = o;
}

extern "C" void kernel_launch(void* const* d_in, const int* in_sizes, int n_in,
                              void* d_out, int out_size, void* d_ws, size_t ws_size,
                              hipStream_t stream)
{
  const float* Q  = (const float*)d_in[0];
  const float* K  = (const float*)d_in[1];
  const float* V  = (const float*)d_in[2];
  const float* WQ = (const float*)d_in[3];
  const float* WK = (const float*)d_in[4];
  const float* WV = (const float*)d_in[5];
  float* out = (float*)d_out;

  const size_t MB = 1ull << 20;
  char* w = (char*)d_ws;
  if (ws_size < 326 * MB) {
    fprintf(stderr, "kernel_launch: workspace too small (%zu B, need >= %zu B)\n",
            ws_size, (size_t)(326 * MB));
    return;
  }

  // ws layout (MB): [0,6) weights bf16 | [6,70) Qd_t | [70,134) Kd_t |
  // [134,198) Vd | [198,326) S bf16 all 16 batches (in-place softmax, no P).
  u16* wq  = (u16*)(w + 0 * MB);
  u16* wk  = (u16*)(w + 2 * MB);
  u16* wv  = (u16*)(w + 4 * MB);
  u16* qdt = (u16*)(w + 6 * MB);
  u16* kdt = (u16*)(w + 70 * MB);
  u16* vd  = (u16*)(w + 134 * MB);
  u16* S   = (u16*)(w + 198 * MB);

  conv_weights<<<dim3(1024, 3), 256, 0, stream>>>(WQ, WK, WV, wq, wk, wv);

  // Projections with FUSED transpose+cvt (no conv_transpose pass):
  // Qd_t/Kd_t (b*2048+s, o): TMODE=1 (A = trans(Q/K) from fp32), B = weights.
  gemm_bt<true, true, false, false, false, 1><<<dim3(4, 128, 1), 512, 0, stream>>>(
      wq, wq, Q, qdt, 1024, 0, 1024, 1024, 0, 0, 0, 1.0f);
  gemm_bt<true, true, false, false, false, 1><<<dim3(4, 128, 1), 512, 0, stream>>>(
      wk, wk, K, kdt, 1024, 0, 1024, 1024, 0, 0, 0, 1.0f);
  // Vd (o, s) per batch: TMODE=2 (B = trans(V) from fp32), A = wv.
  gemm_bt<true, true, false, false, false, 2><<<dim3(8, 4, 16), 512, 0, stream>>>(
      wv, wv, V, vd, 1024, 1024, 0, 2048,
      0, 0, (long long)1024 * 2048, 1.0f);

  // S'[t,s] = Kd_t[t,:]·Qd_t[s,:]/32 — compact triangular grid, 36 tiles/z
  // x 16 z = 576 blocks, chunked XCD swizzle (one batch pair per XCD).
  gemm_bt<true, true, true, false, false, 0><<<dim3(36, 1, 16), 512, 0, stream>>>(
      kdt, qdt, nullptr, S, 1024, 1024, 1024, 2048,
      (long long)2048 * 1024, (long long)2048 * 1024, (long long)2048 * 2048, 0.03125f);
  // row-softmax over s (masked by index), IN PLACE
  col_softmax<<<dim3(2048, 16), 256, 0, stream>>>(S, S);
  // out[o,t] = sum_s Vd[o,s] P[t,s] — single dispatch, causal K-limit,
  // tb descending on slowest axis -> LPT balance (no split-K: r11's +=
  // epilogue added a 256MB RMW and cost more than LPT gained).
  gemm_bt<false, false, false, true, true, 0><<<dim3(16, 4, 8), 512, 0, stream>>>(
      vd, S, nullptr, out, 2048, 2048, 2048, 2048,
      (long long)1024 * 2048, (long long)2048 * 2048, (long long)1024 * 2048, 1.0f);
}

// Round 13
// 564.347 us; speedup vs baseline: 1.1860x; 1.0037x over previous
//
#include <hip/hip_runtime.h>
#include <cstdio>
#include <math.h>

typedef unsigned short u16;
typedef float f32x4 __attribute__((ext_vector_type(4)));
typedef __bf16 bf16x8 __attribute__((ext_vector_type(8)));
typedef u16 u16x4 __attribute__((ext_vector_type(4)));
typedef u16 u16x8 __attribute__((ext_vector_type(8)));

__device__ __forceinline__ u16 f2bf(float x) {
  unsigned u = __float_as_uint(x);
  u = (u + 0x7FFFu + ((u >> 16) & 1u)) >> 16;
  return (u16)u;
}
__device__ __forceinline__ float bf2f(u16 x) {
  return __uint_as_float(((unsigned)x) << 16);
}

__device__ __forceinline__ f32x4 mfma_bf16(bf16x8 a, bf16x8 b, f32x4 c) {
  return __builtin_amdgcn_mfma_f32_16x16x32_bf16(a, b, c, 0, 0, 0);
}

// async global->LDS, 16B per lane. LDS dest = wave-uniform base + lane*16.
__device__ __forceinline__ void gload_lds16(const void* g, void* l) {
  __builtin_amdgcn_global_load_lds(
      (const __attribute__((address_space(1))) void*)g,
      (__attribute__((address_space(3))) void*)l, 16, 0, 0);
}

// C[m,n] = scale * sum_k A[m,k] * B[n,k].  BM=BN=256, BK=64, 512 thr = 8 waves
// (2M x 4N), per-wave 128x64 out. LDS 128KB = 2 buf x {A 32K + B' 32K}.
//
// TMODE=0 (bf16 A,B both K-contig): r10-proven counted-vmcnt 4-phase loop.
// TMODE=1/2: operand A/B fused TRANSPOSE+CVT from fp32 k-major source Tf
//  ([k][2048]). Per tile per wave: 8 coalesced dwordx4, register transpose,
//  32 f2bf, 4 ds_write_b128.
//  r13 fix: TCVT moved OFF the critical path — after ph3's MFMA, VM(2)
//  retires exactly the 8 TLOADs (FIFO; the 2 STAGE DMAs stay in flight) and
//  TCVT(nxb) runs there, overlapping ph4. Legal: buf^1's last ds_reads
//  completed before the barrier ending tile t-1; STAGE DMA writes a disjoint
//  region. End-of-tile: VM(0) (2 DMAs issued a full tile ago -> no stall) +
//  lgkmcnt(0) (ds_write visibility) + barrier.  (r12 had VM(0)+TCVT+lgkm all
//  serial between last MFMA and barrier -> proj stuck at 138us.)
// Swizzle: gload-staged regions: slot ^= row&7 (pre-swizzled source).
//  Reg-written regions: f(row) = (row&7)^((row>>2)&7) (uniform over read- and
//  write-varying row bits). Read offsets match per-operand formula.
// Block-index modes:
//  PVLPT: grid (x=z, y=o-mblock, z=tbidx), bx = 7-blockIdx.z (descending ->
//    LPT: big t-blocks dispatch first).
//  TRI: compact causal grid, gridDim.x == 36 tiles of 8x8 triangular tiling.
//  SWZ: chunked XCD swizzle on flattened id (identity unless nwg%8==0).
template <bool BF16OUT, bool SWZ, bool TRI, bool KLIMIT, bool PVLPT, int TMODE>
__global__ __launch_bounds__(512, 2) void gemm_bt(
    const u16* __restrict__ A, const u16* __restrict__ B,
    const float* __restrict__ Tf, void* __restrict__ Cv,
    int K, int lda, int ldb, int ldc,
    long long sAz, long long sBz, long long sCz, float scale)
{
  int bx, by, z;
  if (PVLPT) {
    z = (int)blockIdx.x; by = (int)blockIdx.y; bx = 7 - (int)blockIdx.z;
  } else {
    const int gx = gridDim.x, gy = gridDim.y;
    const int nwg = gx * gy * gridDim.z;
    int f = blockIdx.x + gx * (blockIdx.y + gy * blockIdx.z);
    if (SWZ && (nwg & 7) == 0) f = (f & 7) * (nwg >> 3) + (f >> 3);
    if (TRI) {
      const int j = f % gx;  // gx == 36
      z = f / gx;
      int r = (int)((sqrtf(8.f * j + 1.f) - 1.f) * 0.5f);
      while (r * (r + 1) / 2 > j) --r;
      while ((r + 1) * (r + 2) / 2 <= j) ++r;
      by = r;
      bx = j - r * (r + 1) / 2;
    } else {
      bx = f % gx;
      const int rest = f / gx;
      by = rest % gy;
      z = rest / gy;
    }
  }

  const int n0 = bx * 256;
  const int m0 = by * 256;
  A += (long long)z * sAz;
  B += (long long)z * sBz;

  const int tid = threadIdx.x;
  const int wave = tid >> 6, lane = tid & 63;
  const int wr = wave >> 2, wc = wave & 3;  // 2M x 4N wave grid

  // per buffer (32768 u16): A [256][64] at 0..16383; B' halves at 16384 +
  // half*8192 + r'[0..127]*64.
  __shared__ u16 lds[2][32768];

  f32x4 acc[8][4] = {};

  int kEnd = K;
  if (KLIMIT || PVLPT) { int ke = n0 + 256; kEnd = ke < K ? ke : K; }
  const int nt = kEnd >> 6;

  // ---- gload staging (old swizzle slot^=row&7, pre-swizzled source):
  const int sOff = ((lane & 7) ^ ((lane >> 3) & 7)) * 8;  // elem offset in row
  const int r0 = wave * 8 + (lane >> 3);                  // row within call
  const u16* gA0 = A + (long long)(m0 + r0) * lda + sOff;

  // ---- transpose source (fp32, [k][2048])
  const float* Tsrc = nullptr;
  if (TMODE == 1) Tsrc = Tf + ((long long)(m0 >> 11) * 1024) * 2048 + (m0 & 2047);
  else if (TMODE == 2) Tsrc = Tf + ((long long)z * 1024) * 2048 + n0;
  const int tcol = lane * 4;
  f32x4 tv[8];

  // ---- read offsets. frag rows: A: wr*128+m*16+frow; B': wc*32+(n&1)*16+frow.
  const int frow = lane & 15, g = lane >> 4;
  const int swzA0 = (TMODE == 1) ? ((frow & 7) ^ (frow >> 2)) : (frow & 7);
  const int swzA1 = (TMODE == 1) ? ((frow & 7) ^ (4 + (frow >> 2))) : (frow & 7);
  const int swzB0 = (TMODE == 2) ? ((frow & 7) ^ (frow >> 2)) : (frow & 7);
  const int swzB1 = (TMODE == 2) ? ((frow & 7) ^ (4 + (frow >> 2))) : (frow & 7);

#define AOFF(m, kk) ((wr * 128 + (m) * 16 + frow) * 64 + \
                     (((kk) * 4 + g) ^ (((m) & 1) ? swzA1 : swzA0)) * 8)
#define BOFF(n, kk) (16384 + ((n) >> 1) * 8192 + (wc * 32 + ((n) & 1) * 16 + frow) * 64 + \
                     (((kk) * 4 + g) ^ (((n) & 1) ? swzB1 : swzB0)) * 8)

#define STAGE_A(T, BUF, H)                                                     \
  {                                                                            \
    const long long kc = (long long)(T) * 64;                                  \
    _Pragma("unroll")                                                          \
    for (int c = (H) * 2; c < (H) * 2 + 2; ++c)                                \
      gload_lds16(gA0 + (long long)(c * 64) * lda + kc,                        \
                  &lds[BUF][c * 4096 + wave * 512]);                           \
  }
#define STAGE_B(T, BUF, H)                                                     \
  {                                                                            \
    const long long kc = (long long)(T) * 64;                                  \
    _Pragma("unroll")                                                          \
    for (int c = (H) * 2; c < (H) * 2 + 2; ++c) {                              \
      const int rp = (c & 1) * 64 + r0;                                        \
      const int row = (rp >> 5) * 64 + (c >> 1) * 32 + (rp & 31);              \
      gload_lds16(B + (long long)(n0 + row) * ldb + sOff + kc,                 \
                  &lds[BUF][16384 + c * 4096 + wave * 512]);                   \
    }                                                                          \
  }
// issue 8 fp32 rows of tile T (k = T*64 + wave*8 + r)
#define TLOAD(T)                                                               \
  _Pragma("unroll")                                                            \
  for (int r = 0; r < 8; ++r)                                                  \
    tv[r] = *(const f32x4*)(Tsrc + (long long)((T) * 64 + wave * 8 + r) * 2048 + tcol);
// cvt + transpose-in-regs + 4 x ds_write_b128 into buf BUF
#define TCVT(BUF)                                                              \
  _Pragma("unroll")                                                            \
  for (int j = 0; j < 4; ++j) {                                                \
    const int rw = (lane << 2) + j;                                            \
    u16x8 hv;                                                                  \
    _Pragma("unroll")                                                          \
    for (int r = 0; r < 8; ++r) hv[r] = f2bf(tv[r][j]);                        \
    int ad;                                                                    \
    if (TMODE == 1) {                                                          \
      ad = rw * 64 + ((wave ^ ((rw & 7) ^ ((rw >> 2) & 7))) * 8);              \
    } else {                                                                   \
      const int h = (rw >> 5) & 1, rp = (rw >> 6) * 32 + (rw & 31);            \
      ad = 16384 + h * 8192 + rp * 64 +                                        \
           ((wave ^ ((rp & 7) ^ ((rp >> 2) & 7))) * 8);                        \
    }                                                                          \
    *(u16x8*)(&lds[BUF][ad]) = hv;                                             \
  }

  bf16x8 pA[8], pB[4];
#define READ_A(mb)                                                             \
  _Pragma("unroll")                                                            \
  for (int i = 0; i < 4; ++i) {                                                \
    pA[i * 2 + 0] = *(const bf16x8*)(bb + AOFF((mb) + i, 0));                  \
    pA[i * 2 + 1] = *(const bf16x8*)(bb + AOFF((mb) + i, 1));                  \
  }
#define READ_B(nb)                                                             \
  _Pragma("unroll")                                                            \
  for (int i = 0; i < 2; ++i) {                                                \
    pB[i * 2 + 0] = *(const bf16x8*)(bb + BOFF((nb) + i, 0));                  \
    pB[i * 2 + 1] = *(const bf16x8*)(bb + BOFF((nb) + i, 1));                  \
  }
#define MFMA16(mb, nb)                                                         \
  _Pragma("unroll")                                                            \
  for (int i = 0; i < 4; ++i)                                                  \
    _Pragma("unroll")                                                          \
    for (int j = 0; j < 2; ++j) {                                              \
      acc[(mb) + i][(nb) + j] =                                                \
          mfma_bf16(pA[i * 2 + 0], pB[j * 2 + 0], acc[(mb) + i][(nb) + j]);    \
      acc[(mb) + i][(nb) + j] =                                                \
          mfma_bf16(pA[i * 2 + 1], pB[j * 2 + 1], acc[(mb) + i][(nb) + j]);    \
    }

#define BAR()  __builtin_amdgcn_s_barrier()
#define LGKM0()                                                                \
  asm volatile("s_waitcnt lgkmcnt(0)" ::: "memory");                           \
  __builtin_amdgcn_sched_barrier(0)
#define VM(N) asm volatile("s_waitcnt vmcnt(" #N ")" ::: "memory")

  if constexpr (TMODE == 0) {
    // ---- r10-proven counted-vmcnt loop (bf16 operands, gload both) ----
    STAGE_A(0, 0, 0) STAGE_A(0, 0, 1) STAGE_B(0, 0, 0) STAGE_B(0, 0, 1)
    VM(2);
    BAR();
    for (int t = 0; t < nt; ++t) {
      const u16* bb = &lds[t & 1][0];
      const int nxb = (t + 1) & 1;
      const bool pf = (t + 1 < nt);

      READ_A(0) READ_B(0)
      if (pf) STAGE_A(t + 1, nxb, 0)
      BAR(); LGKM0();
      __builtin_amdgcn_s_setprio(1); MFMA16(0, 0); __builtin_amdgcn_s_setprio(0);
      if (pf) VM(2); else VM(0);
      BAR();

      READ_B(2)
      if (pf) STAGE_A(t + 1, nxb, 1)
      BAR(); LGKM0();
      __builtin_amdgcn_s_setprio(1); MFMA16(0, 2); __builtin_amdgcn_s_setprio(0);
      BAR();

      READ_A(4)
      if (pf) STAGE_B(t + 1, nxb, 0)
      BAR(); LGKM0();
      __builtin_amdgcn_s_setprio(1); MFMA16(4, 2); __builtin_amdgcn_s_setprio(0);
      BAR();

      READ_B(0)
      if (pf) STAGE_B(t + 1, nxb, 1)
      BAR(); LGKM0();
      __builtin_amdgcn_s_setprio(1); MFMA16(4, 0); __builtin_amdgcn_s_setprio(0);
      if (pf) VM(2); else VM(0);
      BAR();
    }
  } else {
    // ---- fused-transpose loop (r13: TCVT overlapped, not serial) ----
    TLOAD(0)
    if (TMODE == 1) { STAGE_B(0, 0, 0) STAGE_B(0, 0, 1) }
    else            { STAGE_A(0, 0, 0) STAGE_A(0, 0, 1) }
    VM(0);
    TCVT(0)
    asm volatile("s_waitcnt lgkmcnt(0)" ::: "memory");
    BAR();
    for (int t = 0; t < nt; ++t) {
      const u16* bb = &lds[t & 1][0];
      const int nxb = (t + 1) & 1;
      const bool pf = (t + 1 < nt);

      if (pf) {
        TLOAD(t + 1)   // 8 dwordx4 (issued first -> oldest in VMEM FIFO)
        if (TMODE == 1) { STAGE_B(t + 1, nxb, 0) STAGE_B(t + 1, nxb, 1) }
        else            { STAGE_A(t + 1, nxb, 0) STAGE_A(t + 1, nxb, 1) }
      }

      READ_A(0) READ_B(0)
      BAR(); LGKM0();
      __builtin_amdgcn_s_setprio(1); MFMA16(0, 0); __builtin_amdgcn_s_setprio(0);
      BAR();

      READ_B(2)
      BAR(); LGKM0();
      __builtin_amdgcn_s_setprio(1); MFMA16(0, 2); __builtin_amdgcn_s_setprio(0);
      BAR();

      READ_A(4)
      BAR(); LGKM0();
      __builtin_amdgcn_s_setprio(1); MFMA16(4, 2); __builtin_amdgcn_s_setprio(0);
      // overlap zone: retire the 8 TLOADs only (2 STAGE DMAs stay in flight),
      // then convert+write t+1's transposed operand while ph4 proceeds.
      if (pf) { VM(2); TCVT(nxb) }
      BAR();

      READ_B(0)
      BAR(); LGKM0();
      __builtin_amdgcn_s_setprio(1); MFMA16(4, 0); __builtin_amdgcn_s_setprio(0);
      VM(0);  // 2 DMAs issued a full tile ago -> no stall
      asm volatile("s_waitcnt lgkmcnt(0)" ::: "memory");  // TCVT writes visible
      BAR();
    }
  }
#undef STAGE_A
#undef STAGE_B
#undef TLOAD
#undef TCVT
#undef READ_A
#undef READ_B
#undef MFMA16
#undef AOFF
#undef BOFF
#undef BAR
#undef LGKM0
#undef VM

  // C/D layout: col = lane&15, row = (lane>>4)*4 + r  [m89-verified]
  const int crow0 = m0 + wr * 128 + (lane >> 4) * 4;
  const int ccol0 = n0 + wc * 64 + (lane & 15);
  if (BF16OUT) {
    u16* C = (u16*)Cv + (long long)z * sCz;
#pragma unroll
    for (int m = 0; m < 8; ++m)
#pragma unroll
      for (int n = 0; n < 4; ++n)
#pragma unroll
        for (int r = 0; r < 4; ++r)
          C[(long long)(crow0 + m * 16 + r) * ldc + ccol0 + n * 16] = f2bf(acc[m][n][r] * scale);
  } else {
    float* C = (float*)Cv + (long long)z * sCz;
#pragma unroll
    for (int m = 0; m < 8; ++m)
#pragma unroll
      for (int n = 0; n < 4; ++n)
#pragma unroll
        for (int r = 0; r < 4; ++r)
          C[(long long)(crow0 + m * 16 + r) * ldc + ccol0 + n * 16] = acc[m][n][r] * scale;
  }
}

__global__ __launch_bounds__(256) void conv_weights(
    const float* __restrict__ a, const float* __restrict__ b, const float* __restrict__ c,
    u16* __restrict__ oa, u16* __restrict__ ob, u16* __restrict__ oc)
{
  const int which = blockIdx.y;
  const float* s = which == 0 ? a : which == 1 ? b : c;
  u16* d = which == 0 ? oa : which == 1 ? ob : oc;
  const int idx = (blockIdx.x * 256 + threadIdx.x) * 4;
  f32x4 v = *(const f32x4*)(s + idx);
  u16x4 o;
#pragma unroll
  for (int j = 0; j < 4; ++j) o[j] = f2bf(v[j]);
  *(u16x4*)(d + idx) = o;
}

// Row t of S'[t,s] (bf16): mask by index (s<=t), max, sum-exp, write P bf16
// IN PLACE (each thread reads only its own 8 elems before writing them).
__global__ __launch_bounds__(256) void col_softmax(const u16* __restrict__ S, u16* __restrict__ P)
{
  const int t = blockIdx.x;
  const long long rowOff = ((long long)blockIdx.y * 2048 + t) * 2048;
  const u16* row = S + rowOff;
  u16* prow = P + rowOff;
  const int tid = threadIdx.x;
  const int i0 = tid * 8;

  u16x8 a = *(const u16x8*)(row + i0);
  float v[8];
#pragma unroll
  for (int j = 0; j < 8; ++j)
    v[j] = (i0 + j <= t) ? bf2f(a[j]) : -1e30f;  // unwritten/masked discarded by index

  float m = v[0];
#pragma unroll
  for (int j = 1; j < 8; ++j) m = fmaxf(m, v[j]);
#pragma unroll
  for (int off = 32; off; off >>= 1) m = fmaxf(m, __shfl_xor(m, off));
  __shared__ float red[4];
  __shared__ float red2[4];
  if ((tid & 63) == 0) red[tid >> 6] = m;
  __syncthreads();
  m = fmaxf(fmaxf(red[0], red[1]), fmaxf(red[2], red[3]));

  float e[8]; float ssum = 0.f;
#pragma unroll
  for (int j = 0; j < 8; ++j) { e[j] = __expf(v[j] - m); ssum += e[j]; }
#pragma unroll
  for (int off = 32; off; off >>= 1) ssum += __shfl_xor(ssum, off);
  if ((tid & 63) == 0) red2[tid >> 6] = ssum;
  __syncthreads();
  ssum = red2[0] + red2[1] + red2[2] + red2[3];
  const float inv = 1.0f / ssum;
  u16x8 o;
#pragma unroll
  for (int j = 0; j < 8; ++j) o[j] = f2bf(e[j] * inv);
  *(u16x8*)(prow + i0) = o;
}

extern "C" void kernel_launch(void* const* d_in, const int* in_sizes, int n_in,
                              void* d_out, int out_size, void* d_ws, size_t ws_size,
                              hipStream_t stream)
{
  const float* Q  = (const float*)d_in[0];
  const float* K  = (const float*)d_in[1];
  const float* V  = (const float*)d_in[2];
  const float* WQ = (const float*)d_in[3];
  const float* WK = (const float*)d_in[4];
  const float* WV = (const float*)d_in[5];
  float* out = (float*)d_out;

  const size_t MB = 1ull << 20;
  char* w = (char*)d_ws;
  if (ws_size < 326 * MB) {
    fprintf(stderr, "kernel_launch: workspace too small (%zu B, need >= %zu B)\n",
            ws_size, (size_t)(326 * MB));
    return;
  }

  // ws layout (MB): [0,6) weights bf16 | [6,70) Qd_t | [70,134) Kd_t |
  // [134,198) Vd | [198,326) S bf16 all 16 batches (in-place softmax, no P).
  u16* wq  = (u16*)(w + 0 * MB);
  u16* wk  = (u16*)(w + 2 * MB);
  u16* wv  = (u16*)(w + 4 * MB);
  u16* qdt = (u16*)(w + 6 * MB);
  u16* kdt = (u16*)(w + 70 * MB);
  u16* vd  = (u16*)(w + 134 * MB);
  u16* S   = (u16*)(w + 198 * MB);

  conv_weights<<<dim3(1024, 3), 256, 0, stream>>>(WQ, WK, WV, wq, wk, wv);

  // Projections with FUSED transpose+cvt (no conv_transpose pass):
  // Qd_t/Kd_t (b*2048+s, o): TMODE=1 (A = trans(Q/K) from fp32), B = weights.
  gemm_bt<true, true, false, false, false, 1><<<dim3(4, 128, 1), 512, 0, stream>>>(
      wq, wq, Q, qdt, 1024, 0, 1024, 1024, 0, 0, 0, 1.0f);
  gemm_bt<true, true, false, false, false, 1><<<dim3(4, 128, 1), 512, 0, stream>>>(
      wk, wk, K, kdt, 1024, 0, 1024, 1024, 0, 0, 0, 1.0f);
  // Vd (o, s) per batch: TMODE=2 (B = trans(V) from fp32), A = wv.
  gemm_bt<true, true, false, false, false, 2><<<dim3(8, 4, 16), 512, 0, stream>>>(
      wv, wv, V, vd, 1024, 1024, 0, 2048,
      0, 0, (long long)1024 * 2048, 1.0f);

  // S'[t,s] = Kd_t[t,:]·Qd_t[s,:]/32 — compact triangular grid, 36 tiles/z
  // x 16 z = 576 blocks, chunked XCD swizzle (one batch pair per XCD).
  gemm_bt<true, true, true, false, false, 0><<<dim3(36, 1, 16), 512, 0, stream>>>(
      kdt, qdt, nullptr, S, 1024, 1024, 1024, 2048,
      (long long)2048 * 1024, (long long)2048 * 1024, (long long)2048 * 2048, 0.03125f);
  // row-softmax over s (masked by index), IN PLACE
  col_softmax<<<dim3(2048, 16), 256, 0, stream>>>(S, S);
  // out[o,t] = sum_s Vd[o,s] P[t,s] — single dispatch, causal K-limit,
  // tb descending on slowest axis -> LPT balance.
  gemm_bt<false, false, false, true, true, 0><<<dim3(16, 4, 8), 512, 0, stream>>>(
      vd, S, nullptr, out, 2048, 2048, 2048, 2048,
      (long long)1024 * 2048, (long long)2048 * 2048, (long long)1024 * 2048, 1.0f);
}

// Round 14
// 563.871 us; speedup vs baseline: 1.1870x; 1.0008x over previous
//
#include <hip/hip_runtime.h>
#include <cstdio>
#include <math.h>

typedef unsigned short u16;
typedef float f32x4 __attribute__((ext_vector_type(4)));
typedef __bf16 bf16x8 __attribute__((ext_vector_type(8)));
typedef u16 u16x4 __attribute__((ext_vector_type(4)));
typedef u16 u16x8 __attribute__((ext_vector_type(8)));

__device__ __forceinline__ u16 f2bf(float x) {
  unsigned u = __float_as_uint(x);
  u = (u + 0x7FFFu + ((u >> 16) & 1u)) >> 16;
  return (u16)u;
}
__device__ __forceinline__ float bf2f(u16 x) {
  return __uint_as_float(((unsigned)x) << 16);
}

__device__ __forceinline__ f32x4 mfma_bf16(bf16x8 a, bf16x8 b, f32x4 c) {
  return __builtin_amdgcn_mfma_f32_16x16x32_bf16(a, b, c, 0, 0, 0);
}

// async global->LDS, 16B per lane. LDS dest = wave-uniform base + lane*16.
__device__ __forceinline__ void gload_lds16(const void* g, void* l) {
  __builtin_amdgcn_global_load_lds(
      (const __attribute__((address_space(1))) void*)g,
      (__attribute__((address_space(3))) void*)l, 16, 0, 0);
}

// C[m,n] = scale * sum_k A[m,k] * B[n,k].  BM=BN=256, BK=64, 512 thr = 8 waves
// (2M x 4N), per-wave 128x64 out. LDS 128KB = 2 buf x {A 32K + B' 32K}.
//
// r14 change (only): UNPIN the scheduler. r10-r13 had lgkmcnt(0) +
// sched_barrier(0) after every phase barrier — rule #18 applies to inline-asm
// ds_reads only; ours are compiler-visible loads, so the compiler already
// inserts fine-grained partial lgkmcnt(N) for ds_read->MFMA deps (m97). The
// sched_barrier(0) x8/tile pinned the schedule (m141 failure mode: no
// ds_read/MFMA overlap, no cross-phase pipelining). Now: phase barrier =
// asm s_barrier with "memory" clobber (blocks memory-op hoisting across the
// barrier — r8-proven) and NO forced lgkm/sched drains. Counted vmcnt waits
// (DMA completion is compiler-invisible) and TCVT-visibility lgkmcnt stay.
//
// TMODE=0 (bf16 A,B both K-contig): counted-vmcnt 4-phase loop; per phase
//   {ds-read quadrant; stage half-tile; s_barrier; setprio(1); 16 MFMA;
//    setprio(0); [counted vmcnt]; s_barrier}. Waits: end-ph1 vmcnt(2)
//   retires B-hi'(t); end-ph4 vmcnt(2) retires A-lo,A-hi,B-lo'(t+1).
// TMODE=1/2: operand A/B fused TRANSPOSE+CVT from fp32 k-major source Tf
//   ([k][2048]): 8 dwordx4 + reg transpose + 32 f2bf + 4 ds_write_b128;
//   TCVT overlapped after ph3 (VM(2) retires the 8 TLOADs, 2 STAGE DMAs
//   stay in flight); end-of-tile VM(0)+lgkmcnt(0) (write visibility).
// Swizzle: gload-staged regions slot^=row&7 (pre-swizzled source);
//   reg-written regions f(row)=(row&7)^((row>>2)&7). Conflicts measured 0.
// Block-index modes:
//  PVLPT: grid (x=z, y=o-mblock, z=tbidx), bx = 7-blockIdx.z (LPT).
//  TRI: compact causal grid, gridDim.x == 36 tiles of 8x8 triangular tiling.
//  SWZ: chunked XCD swizzle on flattened id (identity unless nwg%8==0).
template <bool BF16OUT, bool SWZ, bool TRI, bool KLIMIT, bool PVLPT, int TMODE>
__global__ __launch_bounds__(512, 2) void gemm_bt(
    const u16* __restrict__ A, const u16* __restrict__ B,
    const float* __restrict__ Tf, void* __restrict__ Cv,
    int K, int lda, int ldb, int ldc,
    long long sAz, long long sBz, long long sCz, float scale)
{
  int bx, by, z;
  if (PVLPT) {
    z = (int)blockIdx.x; by = (int)blockIdx.y; bx = 7 - (int)blockIdx.z;
  } else {
    const int gx = gridDim.x, gy = gridDim.y;
    const int nwg = gx * gy * gridDim.z;
    int f = blockIdx.x + gx * (blockIdx.y + gy * blockIdx.z);
    if (SWZ && (nwg & 7) == 0) f = (f & 7) * (nwg >> 3) + (f >> 3);
    if (TRI) {
      const int j = f % gx;  // gx == 36
      z = f / gx;
      int r = (int)((sqrtf(8.f * j + 1.f) - 1.f) * 0.5f);
      while (r * (r + 1) / 2 > j) --r;
      while ((r + 1) * (r + 2) / 2 <= j) ++r;
      by = r;
      bx = j - r * (r + 1) / 2;
    } else {
      bx = f % gx;
      const int rest = f / gx;
      by = rest % gy;
      z = rest / gy;
    }
  }

  const int n0 = bx * 256;
  const int m0 = by * 256;
  A += (long long)z * sAz;
  B += (long long)z * sBz;

  const int tid = threadIdx.x;
  const int wave = tid >> 6, lane = tid & 63;
  const int wr = wave >> 2, wc = wave & 3;  // 2M x 4N wave grid

  // per buffer (32768 u16): A [256][64] at 0..16383; B' halves at 16384 +
  // half*8192 + r'[0..127]*64.
  __shared__ u16 lds[2][32768];

  f32x4 acc[8][4] = {};

  int kEnd = K;
  if (KLIMIT || PVLPT) { int ke = n0 + 256; kEnd = ke < K ? ke : K; }
  const int nt = kEnd >> 6;

  // ---- gload staging (old swizzle slot^=row&7, pre-swizzled source):
  const int sOff = ((lane & 7) ^ ((lane >> 3) & 7)) * 8;  // elem offset in row
  const int r0 = wave * 8 + (lane >> 3);                  // row within call
  const u16* gA0 = A + (long long)(m0 + r0) * lda + sOff;

  // ---- transpose source (fp32, [k][2048])
  const float* Tsrc = nullptr;
  if (TMODE == 1) Tsrc = Tf + ((long long)(m0 >> 11) * 1024) * 2048 + (m0 & 2047);
  else if (TMODE == 2) Tsrc = Tf + ((long long)z * 1024) * 2048 + n0;
  const int tcol = lane * 4;
  f32x4 tv[8];

  // ---- read offsets. frag rows: A: wr*128+m*16+frow; B': wc*32+(n&1)*16+frow.
  const int frow = lane & 15, g = lane >> 4;
  const int swzA0 = (TMODE == 1) ? ((frow & 7) ^ (frow >> 2)) : (frow & 7);
  const int swzA1 = (TMODE == 1) ? ((frow & 7) ^ (4 + (frow >> 2))) : (frow & 7);
  const int swzB0 = (TMODE == 2) ? ((frow & 7) ^ (frow >> 2)) : (frow & 7);
  const int swzB1 = (TMODE == 2) ? ((frow & 7) ^ (4 + (frow >> 2))) : (frow & 7);

#define AOFF(m, kk) ((wr * 128 + (m) * 16 + frow) * 64 + \
                     (((kk) * 4 + g) ^ (((m) & 1) ? swzA1 : swzA0)) * 8)
#define BOFF(n, kk) (16384 + ((n) >> 1) * 8192 + (wc * 32 + ((n) & 1) * 16 + frow) * 64 + \
                     (((kk) * 4 + g) ^ (((n) & 1) ? swzB1 : swzB0)) * 8)

#define STAGE_A(T, BUF, H)                                                     \
  {                                                                            \
    const long long kc = (long long)(T) * 64;                                  \
    _Pragma("unroll")                                                          \
    for (int c = (H) * 2; c < (H) * 2 + 2; ++c)                                \
      gload_lds16(gA0 + (long long)(c * 64) * lda + kc,                        \
                  &lds[BUF][c * 4096 + wave * 512]);                           \
  }
#define STAGE_B(T, BUF, H)                                                     \
  {                                                                            \
    const long long kc = (long long)(T) * 64;                                  \
    _Pragma("unroll")                                                          \
    for (int c = (H) * 2; c < (H) * 2 + 2; ++c) {                              \
      const int rp = (c & 1) * 64 + r0;                                        \
      const int row = (rp >> 5) * 64 + (c >> 1) * 32 + (rp & 31);              \
      gload_lds16(B + (long long)(n0 + row) * ldb + sOff + kc,                 \
                  &lds[BUF][16384 + c * 4096 + wave * 512]);                   \
    }                                                                          \
  }
// issue 8 fp32 rows of tile T (k = T*64 + wave*8 + r)
#define TLOAD(T)                                                               \
  _Pragma("unroll")                                                            \
  for (int r = 0; r < 8; ++r)                                                  \
    tv[r] = *(const f32x4*)(Tsrc + (long long)((T) * 64 + wave * 8 + r) * 2048 + tcol);
// cvt + transpose-in-regs + 4 x ds_write_b128 into buf BUF
#define TCVT(BUF)                                                              \
  _Pragma("unroll")                                                            \
  for (int j = 0; j < 4; ++j) {                                                \
    const int rw = (lane << 2) + j;                                            \
    u16x8 hv;                                                                  \
    _Pragma("unroll")                                                          \
    for (int r = 0; r < 8; ++r) hv[r] = f2bf(tv[r][j]);                        \
    int ad;                                                                    \
    if (TMODE == 1) {                                                          \
      ad = rw * 64 + ((wave ^ ((rw & 7) ^ ((rw >> 2) & 7))) * 8);              \
    } else {                                                                   \
      const int h = (rw >> 5) & 1, rp = (rw >> 6) * 32 + (rw & 31);            \
      ad = 16384 + h * 8192 + rp * 64 +                                        \
           ((wave ^ ((rp & 7) ^ ((rp >> 2) & 7))) * 8);                        \
    }                                                                          \
    *(u16x8*)(&lds[BUF][ad]) = hv;                                             \
  }

  bf16x8 pA[8], pB[4];
#define READ_A(mb)                                                             \
  _Pragma("unroll")                                                            \
  for (int i = 0; i < 4; ++i) {                                                \
    pA[i * 2 + 0] = *(const bf16x8*)(bb + AOFF((mb) + i, 0));                  \
    pA[i * 2 + 1] = *(const bf16x8*)(bb + AOFF((mb) + i, 1));                  \
  }
#define READ_B(nb)                                                             \
  _Pragma("unroll")                                                            \
  for (int i = 0; i < 2; ++i) {                                                \
    pB[i * 2 + 0] = *(const bf16x8*)(bb + BOFF((nb) + i, 0));                  \
    pB[i * 2 + 1] = *(const bf16x8*)(bb + BOFF((nb) + i, 1));                  \
  }
#define MFMA16(mb, nb)                                                         \
  _Pragma("unroll")                                                            \
  for (int i = 0; i < 4; ++i)                                                  \
    _Pragma("unroll")                                                          \
    for (int j = 0; j < 2; ++j) {                                              \
      acc[(mb) + i][(nb) + j] =                                                \
          mfma_bf16(pA[i * 2 + 0], pB[j * 2 + 0], acc[(mb) + i][(nb) + j]);    \
      acc[(mb) + i][(nb) + j] =                                                \
          mfma_bf16(pA[i * 2 + 1], pB[j * 2 + 1], acc[(mb) + i][(nb) + j]);    \
    }

// barrier with memory clobber: ds_reads/writes can't hoist across (r8-proven),
// but register-only MFMA and waitcnt placement stay free for the scheduler.
#define BAR()  asm volatile("s_barrier" ::: "memory")
#define VM(N)  asm volatile("s_waitcnt vmcnt(" #N ")" ::: "memory")
#define LGKMW() asm volatile("s_waitcnt lgkmcnt(0)" ::: "memory")

  if constexpr (TMODE == 0) {
    // ---- counted-vmcnt loop (bf16 operands, gload both) ----
    STAGE_A(0, 0, 0) STAGE_A(0, 0, 1) STAGE_B(0, 0, 0) STAGE_B(0, 0, 1)
    VM(2);
    BAR();
    for (int t = 0; t < nt; ++t) {
      const u16* bb = &lds[t & 1][0];
      const int nxb = (t + 1) & 1;
      const bool pf = (t + 1 < nt);

      READ_A(0) READ_B(0)
      if (pf) STAGE_A(t + 1, nxb, 0)
      BAR();
      __builtin_amdgcn_s_setprio(1); MFMA16(0, 0); __builtin_amdgcn_s_setprio(0);
      if (pf) VM(2); else VM(0);
      BAR();

      READ_B(2)
      if (pf) STAGE_A(t + 1, nxb, 1)
      BAR();
      __builtin_amdgcn_s_setprio(1); MFMA16(0, 2); __builtin_amdgcn_s_setprio(0);
      BAR();

      READ_A(4)
      if (pf) STAGE_B(t + 1, nxb, 0)
      BAR();
      __builtin_amdgcn_s_setprio(1); MFMA16(4, 2); __builtin_amdgcn_s_setprio(0);
      BAR();

      READ_B(0)
      if (pf) STAGE_B(t + 1, nxb, 1)
      BAR();
      __builtin_amdgcn_s_setprio(1); MFMA16(4, 0); __builtin_amdgcn_s_setprio(0);
      if (pf) VM(2); else VM(0);
      BAR();
    }
  } else {
    // ---- fused-transpose loop (TCVT overlapped after ph3) ----
    TLOAD(0)
    if (TMODE == 1) { STAGE_B(0, 0, 0) STAGE_B(0, 0, 1) }
    else            { STAGE_A(0, 0, 0) STAGE_A(0, 0, 1) }
    VM(0);
    TCVT(0)
    LGKMW();
    BAR();
    for (int t = 0; t < nt; ++t) {
      const u16* bb = &lds[t & 1][0];
      const int nxb = (t + 1) & 1;
      const bool pf = (t + 1 < nt);

      if (pf) {
        TLOAD(t + 1)   // 8 dwordx4 (issued first -> oldest in VMEM FIFO)
        if (TMODE == 1) { STAGE_B(t + 1, nxb, 0) STAGE_B(t + 1, nxb, 1) }
        else            { STAGE_A(t + 1, nxb, 0) STAGE_A(t + 1, nxb, 1) }
      }

      READ_A(0) READ_B(0)
      BAR();
      __builtin_amdgcn_s_setprio(1); MFMA16(0, 0); __builtin_amdgcn_s_setprio(0);
      BAR();

      READ_B(2)
      BAR();
      __builtin_amdgcn_s_setprio(1); MFMA16(0, 2); __builtin_amdgcn_s_setprio(0);
      BAR();

      READ_A(4)
      BAR();
      __builtin_amdgcn_s_setprio(1); MFMA16(4, 2); __builtin_amdgcn_s_setprio(0);
      // overlap zone: retire the 8 TLOADs only (2 STAGE DMAs stay in flight),
      // then convert+write t+1's transposed operand while ph4 proceeds.
      if (pf) { VM(2); TCVT(nxb) }
      BAR();

      READ_B(0)
      BAR();
      __builtin_amdgcn_s_setprio(1); MFMA16(4, 0); __builtin_amdgcn_s_setprio(0);
      VM(0);   // 2 DMAs issued a full tile ago -> no stall
      LGKMW(); // TCVT ds_writes visible to other waves
      BAR();
    }
  }
#undef STAGE_A
#undef STAGE_B
#undef TLOAD
#undef TCVT
#undef READ_A
#undef READ_B
#undef MFMA16
#undef AOFF
#undef BOFF
#undef BAR
#undef VM
#undef LGKMW

  // C/D layout: col = lane&15, row = (lane>>4)*4 + r  [m89-verified]
  const int crow0 = m0 + wr * 128 + (lane >> 4) * 4;
  const int ccol0 = n0 + wc * 64 + (lane & 15);
  if (BF16OUT) {
    u16* C = (u16*)Cv + (long long)z * sCz;
#pragma unroll
    for (int m = 0; m < 8; ++m)
#pragma unroll
      for (int n = 0; n < 4; ++n)
#pragma unroll
        for (int r = 0; r < 4; ++r)
          C[(long long)(crow0 + m * 16 + r) * ldc + ccol0 + n * 16] = f2bf(acc[m][n][r] * scale);
  } else {
    float* C = (float*)Cv + (long long)z * sCz;
#pragma unroll
    for (int m = 0; m < 8; ++m)
#pragma unroll
      for (int n = 0; n < 4; ++n)
#pragma unroll
        for (int r = 0; r < 4; ++r)
          C[(long long)(crow0 + m * 16 + r) * ldc + ccol0 + n * 16] = acc[m][n][r] * scale;
  }
}

__global__ __launch_bounds__(256) void conv_weights(
    const float* __restrict__ a, const float* __restrict__ b, const float* __restrict__ c,
    u16* __restrict__ oa, u16* __restrict__ ob, u16* __restrict__ oc)
{
  const int which = blockIdx.y;
  const float* s = which == 0 ? a : which == 1 ? b : c;
  u16* d = which == 0 ? oa : which == 1 ? ob : oc;
  const int idx = (blockIdx.x * 256 + threadIdx.x) * 4;
  f32x4 v = *(const f32x4*)(s + idx);
  u16x4 o;
#pragma unroll
  for (int j = 0; j < 4; ++j) o[j] = f2bf(v[j]);
  *(u16x4*)(d + idx) = o;
}

// Row t of S'[t,s] (bf16): mask by index (s<=t), max, sum-exp, write P bf16
// IN PLACE (each thread reads only its own 8 elems before writing them).
__global__ __launch_bounds__(256) void col_softmax(const u16* __restrict__ S, u16* __restrict__ P)
{
  const int t = blockIdx.x;
  const long long rowOff = ((long long)blockIdx.y * 2048 + t) * 2048;
  const u16* row = S + rowOff;
  u16* prow = P + rowOff;
  const int tid = threadIdx.x;
  const int i0 = tid * 8;

  u16x8 a = *(const u16x8*)(row + i0);
  float v[8];
#pragma unroll
  for (int j = 0; j < 8; ++j)
    v[j] = (i0 + j <= t) ? bf2f(a[j]) : -1e30f;  // unwritten/masked discarded by index

  float m = v[0];
#pragma unroll
  for (int j = 1; j < 8; ++j) m = fmaxf(m, v[j]);
#pragma unroll
  for (int off = 32; off; off >>= 1) m = fmaxf(m, __shfl_xor(m, off));
  __shared__ float red[4];
  __shared__ float red2[4];
  if ((tid & 63) == 0) red[tid >> 6] = m;
  __syncthreads();
  m = fmaxf(fmaxf(red[0], red[1]), fmaxf(red[2], red[3]));

  float e[8]; float ssum = 0.f;
#pragma unroll
  for (int j = 0; j < 8; ++j) { e[j] = __expf(v[j] - m); ssum += e[j]; }
#pragma unroll
  for (int off = 32; off; off >>= 1) ssum += __shfl_xor(ssum, off);
  if ((tid & 63) == 0) red2[tid >> 6] = ssum;
  __syncthreads();
  ssum = red2[0] + red2[1] + red2[2] + red2[3];
  const float inv = 1.0f / ssum;
  u16x8 o;
#pragma unroll
  for (int j = 0; j < 8; ++j) o[j] = f2bf(e[j] * inv);
  *(u16x8*)(prow + i0) = o;
}

extern "C" void kernel_launch(void* const* d_in, const int* in_sizes, int n_in,
                              void* d_out, int out_size, void* d_ws, size_t ws_size,
                              hipStream_t stream)
{
  const float* Q  = (const float*)d_in[0];
  const float* K  = (const float*)d_in[1];
  const float* V  = (const float*)d_in[2];
  const float* WQ = (const float*)d_in[3];
  const float* WK = (const float*)d_in[4];
  const float* WV = (const float*)d_in[5];
  float* out = (float*)d_out;

  const size_t MB = 1ull << 20;
  char* w = (char*)d_ws;
  if (ws_size < 326 * MB) {
    fprintf(stderr, "kernel_launch: workspace too small (%zu B, need >= %zu B)\n",
            ws_size, (size_t)(326 * MB));
    return;
  }

  // ws layout (MB): [0,6) weights bf16 | [6,70) Qd_t | [70,134) Kd_t |
  // [134,198) Vd | [198,326) S bf16 all 16 batches (in-place softmax, no P).
  u16* wq  = (u16*)(w + 0 * MB);
  u16* wk  = (u16*)(w + 2 * MB);
  u16* wv  = (u16*)(w + 4 * MB);
  u16* qdt = (u16*)(w + 6 * MB);
  u16* kdt = (u16*)(w + 70 * MB);
  u16* vd  = (u16*)(w + 134 * MB);
  u16* S   = (u16*)(w + 198 * MB);

  conv_weights<<<dim3(1024, 3), 256, 0, stream>>>(WQ, WK, WV, wq, wk, wv);

  // Projections with FUSED transpose+cvt (no conv_transpose pass):
  // Qd_t/Kd_t (b*2048+s, o): TMODE=1 (A = trans(Q/K) from fp32), B = weights.
  gemm_bt<true, true, false, false, false, 1><<<dim3(4, 128, 1), 512, 0, stream>>>(
      wq, wq, Q, qdt, 1024, 0, 1024, 1024, 0, 0, 0, 1.0f);
  gemm_bt<true, true, false, false, false, 1><<<dim3(4, 128, 1), 512, 0, stream>>>(
      wk, wk, K, kdt, 1024, 0, 1024, 1024, 0, 0, 0, 1.0f);
  // Vd (o, s) per batch: TMODE=2 (B = trans(V) from fp32), A = wv.
  gemm_bt<true, true, false, false, false, 2><<<dim3(8, 4, 16), 512, 0, stream>>>(
      wv, wv, V, vd, 1024, 1024, 0, 2048,
      0, 0, (long long)1024 * 2048, 1.0f);

  // S'[t,s] = Kd_t[t,:]·Qd_t[s,:]/32 — compact triangular grid, 36 tiles/z
  // x 16 z = 576 blocks, chunked XCD swizzle (one batch pair per XCD).
  gemm_bt<true, true, true, false, false, 0><<<dim3(36, 1, 16), 512, 0, stream>>>(
      kdt, qdt, nullptr, S, 1024, 1024, 1024, 2048,
      (long long)2048 * 1024, (long long)2048 * 1024, (long long)2048 * 2048, 0.03125f);
  // row-softmax over s (masked by index), IN PLACE
  col_softmax<<<dim3(2048, 16), 256, 0, stream>>>(S, S);
  // out[o,t] = sum_s Vd[o,s] P[t,s] — single dispatch, causal K-limit,
  // tb descending on slowest axis -> LPT balance.
  gemm_bt<false, false, false, true, true, 0><<<dim3(16, 4, 8), 512, 0, stream>>>(
      vd, S, nullptr, out, 2048, 2048, 2048, 2048,
      (long long)1024 * 2048, (long long)2048 * 2048, (long long)1024 * 2048, 1.0f);
}

// Round 15
// 562.053 us; speedup vs baseline: 1.1908x; 1.0032x over previous
//
#include <hip/hip_runtime.h>
#include <cstdio>
#include <math.h>

typedef unsigned short u16;
typedef float f32x4 __attribute__((ext_vector_type(4)));
typedef __bf16 bf16x8 __attribute__((ext_vector_type(8)));
typedef u16 u16x4 __attribute__((ext_vector_type(4)));
typedef u16 u16x8 __attribute__((ext_vector_type(8)));

__device__ __forceinline__ u16 f2bf(float x) {
  unsigned u = __float_as_uint(x);
  u = (u + 0x7FFFu + ((u >> 16) & 1u)) >> 16;
  return (u16)u;
}
__device__ __forceinline__ float bf2f(u16 x) {
  return __uint_as_float(((unsigned)x) << 16);
}

__device__ __forceinline__ f32x4 mfma_bf16(bf16x8 a, bf16x8 b, f32x4 c) {
  return __builtin_amdgcn_mfma_f32_16x16x32_bf16(a, b, c, 0, 0, 0);
}

// async global->LDS, 16B per lane. LDS dest = wave-uniform base + lane*16.
__device__ __forceinline__ void gload_lds16(const void* g, void* l) {
  __builtin_amdgcn_global_load_lds(
      (const __attribute__((address_space(1))) void*)g,
      (__attribute__((address_space(3))) void*)l, 16, 0, 0);
}

// C[m,n] = scale * sum_k A[m,k] * B[n,k].  BM=BN=256, BK=64, 512 thr = 8 waves
// (2M x 4N), per-wave 128x64 out. LDS 128KB = 2 buf x {A 32K + B' 32K};
// tile t lives in buf[t&1] (even->buf0, odd->buf1).
//
// r15 (TMODE=0 only): faithful 8-phase / 2-K-tile schedule (m201 port).
// Six schedule variants r7-r14 all pinned at 2.85us/tile; m201 runs 1.4us.
// Diagnosis: 1-tile stage lead + draining vmcnt to <=2 twice/tile starves
// the DMA stream. Fix: consume pair (2j,2j+1) while staging pair (2j+2,2j+3)
// with ~2-tile lead; ONE vmcnt(6) per 4 phases (boundaries ph4/ph8).
// Chunks (2 loads each): A0 = frag rows of m0-3 (calls 0,2), A1 = m4-7
// (calls 1,3), Blo' = n0-1 rows (calls 0,1), Bhi' = n2-3 (calls 2,3).
// Consumption: ph1/5: A0+Blo (12 b128); ph2/6: Bhi (4); ph3/7: A1 (8);
// ph4/8: regs only (Blo held in pBlo). Stage slots (iter j, for pair j+1):
//   ph2: Blo(t+2)  ph3: Bhi(t+2)  ph4: A1(t+2)  ph5: A0(t+2)
//   ph6: A0(t+3)+Blo(t+3)  ph7: Bhi(t+3)  ph8: A1(t+3)
// Each region staged ONE phase after its last ds_read (strictly after that
// phase's barrier -> no read/DMA race). Retirement proof (vmcnt counts
// LOADS; VM(6) keeps newest 6 = 3 chunks):
//   ph8(j) retires <= ph6-first  => Blo/Bhi/A1/A0(t+2), A0(t+3) ready for
//     ph1,2,3,5(j+1) reads   [consumed ph1/ph2/ph3/ph1/ph5]
//   ph4(j+1) retires <= ph1(j+1) => Blo(t+3),Bhi(t+3),A1(t+3) ready for
//     ph5/ph6/ph7(j+1)
// Prologue: stage t0,t1 (16 loads), VM(8) retires t0, barrier. Tail: last
// iter boundaries use VM(0). Requires nt EVEN (all our TMODE=0 launches:
// S nt=16, PV nt=(tb+1)*4).
//
// TMODE=1/2 (proj, unchanged r14): fused TRANSPOSE+CVT from fp32 k-major
// source Tf ([k][2048]); 4-phase loop, TCVT overlapped after ph3.
// Swizzle: gload-staged regions slot^=row&7 (pre-swizzled source);
//   reg-written regions f(row)=(row&7)^((row>>2)&7). Conflicts measured 0.
// Block-index modes:
//  PVLPT: grid (x=z, y=o-mblock, z=tbidx), bx = 7-blockIdx.z (LPT).
//  TRI: compact causal grid, gridDim.x == 36 tiles of 8x8 triangular tiling.
//  SWZ: chunked XCD swizzle on flattened id (identity unless nwg%8==0).
template <bool BF16OUT, bool SWZ, bool TRI, bool KLIMIT, bool PVLPT, int TMODE>
__global__ __launch_bounds__(512, 2) void gemm_bt(
    const u16* __restrict__ A, const u16* __restrict__ B,
    const float* __restrict__ Tf, void* __restrict__ Cv,
    int K, int lda, int ldb, int ldc,
    long long sAz, long long sBz, long long sCz, float scale)
{
  int bx, by, z;
  if (PVLPT) {
    z = (int)blockIdx.x; by = (int)blockIdx.y; bx = 7 - (int)blockIdx.z;
  } else {
    const int gx = gridDim.x, gy = gridDim.y;
    const int nwg = gx * gy * gridDim.z;
    int f = blockIdx.x + gx * (blockIdx.y + gy * blockIdx.z);
    if (SWZ && (nwg & 7) == 0) f = (f & 7) * (nwg >> 3) + (f >> 3);
    if (TRI) {
      const int j = f % gx;  // gx == 36
      z = f / gx;
      int r = (int)((sqrtf(8.f * j + 1.f) - 1.f) * 0.5f);
      while (r * (r + 1) / 2 > j) --r;
      while ((r + 1) * (r + 2) / 2 <= j) ++r;
      by = r;
      bx = j - r * (r + 1) / 2;
    } else {
      bx = f % gx;
      const int rest = f / gx;
      by = rest % gy;
      z = rest / gy;
    }
  }

  const int n0 = bx * 256;
  const int m0 = by * 256;
  A += (long long)z * sAz;
  B += (long long)z * sBz;

  const int tid = threadIdx.x;
  const int wave = tid >> 6, lane = tid & 63;
  const int wr = wave >> 2, wc = wave & 3;  // 2M x 4N wave grid

  // per buffer (32768 u16): A [256][64] at 0..16383; B' halves at 16384 +
  // half*8192 + r'[0..127]*64.
  __shared__ u16 lds[2][32768];

  f32x4 acc[8][4] = {};

  int kEnd = K;
  if (KLIMIT || PVLPT) { int ke = n0 + 256; kEnd = ke < K ? ke : K; }
  const int nt = kEnd >> 6;

  // ---- gload staging (swizzle slot^=row&7, pre-swizzled source):
  const int sOff = ((lane & 7) ^ ((lane >> 3) & 7)) * 8;  // elem offset in row
  const int r0 = wave * 8 + (lane >> 3);                  // row within call
  const u16* gA0 = A + (long long)(m0 + r0) * lda + sOff;

  // ---- transpose source (fp32, [k][2048])
  const float* Tsrc = nullptr;
  if (TMODE == 1) Tsrc = Tf + ((long long)(m0 >> 11) * 1024) * 2048 + (m0 & 2047);
  else if (TMODE == 2) Tsrc = Tf + ((long long)z * 1024) * 2048 + n0;
  const int tcol = lane * 4;
  f32x4 tv[8];

  // ---- read offsets. frag rows: A: wr*128+m*16+frow; B': wc*32+(n&1)*16+frow.
  const int frow = lane & 15, g = lane >> 4;
  const int swzA0 = (TMODE == 1) ? ((frow & 7) ^ (frow >> 2)) : (frow & 7);
  const int swzA1 = (TMODE == 1) ? ((frow & 7) ^ (4 + (frow >> 2))) : (frow & 7);
  const int swzB0 = (TMODE == 2) ? ((frow & 7) ^ (frow >> 2)) : (frow & 7);
  const int swzB1 = (TMODE == 2) ? ((frow & 7) ^ (4 + (frow >> 2))) : (frow & 7);

#define AOFF(m, kk) ((wr * 128 + (m) * 16 + frow) * 64 + \
                     (((kk) * 4 + g) ^ (((m) & 1) ? swzA1 : swzA0)) * 8)
#define BOFF(n, kk) (16384 + ((n) >> 1) * 8192 + (wc * 32 + ((n) & 1) * 16 + frow) * 64 + \
                     (((kk) * 4 + g) ^ (((n) & 1) ? swzB1 : swzB0)) * 8)

// A chunk stagers: A0 = calls 0,2 (frag rows of m0-3); A1 = calls 1,3 (m4-7)
#define STAGE_A0(T, BUF)                                                       \
  {                                                                            \
    const long long kc = (long long)(T) * 64;                                  \
    gload_lds16(gA0 + kc, &lds[BUF][wave * 512]);                              \
    gload_lds16(gA0 + (long long)128 * lda + kc,                               \
                &lds[BUF][2 * 4096 + wave * 512]);                             \
  }
#define STAGE_A1(T, BUF)                                                       \
  {                                                                            \
    const long long kc = (long long)(T) * 64;                                  \
    gload_lds16(gA0 + (long long)64 * lda + kc,                                \
                &lds[BUF][1 * 4096 + wave * 512]);                             \
    gload_lds16(gA0 + (long long)192 * lda + kc,                               \
                &lds[BUF][3 * 4096 + wave * 512]);                             \
  }
#define STAGE_A(T, BUF, H)                                                     \
  {                                                                            \
    const long long kc = (long long)(T) * 64;                                  \
    _Pragma("unroll")                                                          \
    for (int c = (H) * 2; c < (H) * 2 + 2; ++c)                                \
      gload_lds16(gA0 + (long long)(c * 64) * lda + kc,                        \
                  &lds[BUF][c * 4096 + wave * 512]);                           \
  }
#define STAGE_B(T, BUF, H)                                                     \
  {                                                                            \
    const long long kc = (long long)(T) * 64;                                  \
    _Pragma("unroll")                                                          \
    for (int c = (H) * 2; c < (H) * 2 + 2; ++c) {                              \
      const int rp = (c & 1) * 64 + r0;                                        \
      const int row = (rp >> 5) * 64 + (c >> 1) * 32 + (rp & 31);              \
      gload_lds16(B + (long long)(n0 + row) * ldb + sOff + kc,                 \
                  &lds[BUF][16384 + c * 4096 + wave * 512]);                   \
    }                                                                          \
  }
// issue 8 fp32 rows of tile T (k = T*64 + wave*8 + r)
#define TLOAD(T)                                                               \
  _Pragma("unroll")                                                            \
  for (int r = 0; r < 8; ++r)                                                  \
    tv[r] = *(const f32x4*)(Tsrc + (long long)((T) * 64 + wave * 8 + r) * 2048 + tcol);
// cvt + transpose-in-regs + 4 x ds_write_b128 into buf BUF
#define TCVT(BUF)                                                              \
  _Pragma("unroll")                                                            \
  for (int j = 0; j < 4; ++j) {                                                \
    const int rw = (lane << 2) + j;                                            \
    u16x8 hv;                                                                  \
    _Pragma("unroll")                                                          \
    for (int r = 0; r < 8; ++r) hv[r] = f2bf(tv[r][j]);                        \
    int ad;                                                                    \
    if (TMODE == 1) {                                                          \
      ad = rw * 64 + ((wave ^ ((rw & 7) ^ ((rw >> 2) & 7))) * 8);              \
    } else {                                                                   \
      const int h = (rw >> 5) & 1, rp = (rw >> 6) * 32 + (rw & 31);            \
      ad = 16384 + h * 8192 + rp * 64 +                                        \
           ((wave ^ ((rp & 7) ^ ((rp >> 2) & 7))) * 8);                        \
    }                                                                          \
    *(u16x8*)(&lds[BUF][ad]) = hv;                                             \
  }

  bf16x8 pA[8], pBlo[4], pBhi[4];
#define READ_A(base, mb)                                                       \
  _Pragma("unroll")                                                            \
  for (int i = 0; i < 4; ++i) {                                                \
    pA[i * 2 + 0] = *(const bf16x8*)((base) + AOFF((mb) + i, 0));              \
    pA[i * 2 + 1] = *(const bf16x8*)((base) + AOFF((mb) + i, 1));              \
  }
#define READ_BLO(base)                                                         \
  _Pragma("unroll")                                                            \
  for (int i = 0; i < 2; ++i) {                                                \
    pBlo[i * 2 + 0] = *(const bf16x8*)((base) + BOFF(i, 0));                   \
    pBlo[i * 2 + 1] = *(const bf16x8*)((base) + BOFF(i, 1));                   \
  }
#define READ_BHI(base)                                                         \
  _Pragma("unroll")                                                            \
  for (int i = 0; i < 2; ++i) {                                                \
    pBhi[i * 2 + 0] = *(const bf16x8*)((base) + BOFF(2 + i, 0));               \
    pBhi[i * 2 + 1] = *(const bf16x8*)((base) + BOFF(2 + i, 1));               \
  }
#define MFMA16(mb, nb, P)                                                      \
  _Pragma("unroll")                                                            \
  for (int i = 0; i < 4; ++i)                                                  \
    _Pragma("unroll")                                                          \
    for (int j = 0; j < 2; ++j) {                                              \
      acc[(mb) + i][(nb) + j] =                                                \
          mfma_bf16(pA[i * 2 + 0], P[j * 2 + 0], acc[(mb) + i][(nb) + j]);     \
      acc[(mb) + i][(nb) + j] =                                                \
          mfma_bf16(pA[i * 2 + 1], P[j * 2 + 1], acc[(mb) + i][(nb) + j]);     \
    }

#define BAR()   asm volatile("s_barrier" ::: "memory")
#define VM(N)   asm volatile("s_waitcnt vmcnt(" #N ")" ::: "memory")
#define LGKMW() asm volatile("s_waitcnt lgkmcnt(0)" ::: "memory")
#define PRIO1() __builtin_amdgcn_s_setprio(1)
#define PRIO0() __builtin_amdgcn_s_setprio(0)

  if constexpr (TMODE == 0) {
    // ---- 8-phase / 2-K-tile counted-vmcnt pipeline ----
    const u16* b0 = &lds[0][0];
    const u16* b1 = &lds[1][0];
    // prologue: t0 -> buf0, t1 -> buf1 (16 loads); retire t0's 8.
    STAGE_A0(0, 0) STAGE_B(0, 0, 0) STAGE_B(0, 0, 1) STAGE_A1(0, 0)
    STAGE_A0(1, 1) STAGE_B(1, 1, 0) STAGE_B(1, 1, 1) STAGE_A1(1, 1)
    VM(8);
    BAR();
    const int npairs = nt >> 1;
    for (int j = 0; j < npairs; ++j) {
      const int t = 2 * j;
      const bool pf = (j + 1 < npairs);

      // ph1: read A0(t)+Blo(t); MFMA m0-3 x n0-1
      READ_A(b0, 0) READ_BLO(b0)
      BAR(); PRIO1(); MFMA16(0, 0, pBlo); PRIO0(); BAR();
      // ph2: read Bhi(t); stage Blo(t+2); MFMA m0-3 x n2-3
      READ_BHI(b0)
      if (pf) STAGE_B(t + 2, 0, 0)
      BAR(); PRIO1(); MFMA16(0, 2, pBhi); PRIO0(); BAR();
      // ph3: read A1(t); stage Bhi(t+2); MFMA m4-7 x n2-3
      READ_A(b0, 4)
      if (pf) STAGE_B(t + 2, 0, 1)
      BAR(); PRIO1(); MFMA16(4, 2, pBhi); PRIO0(); BAR();
      // ph4: regs only; stage A1(t+2); MFMA m4-7 x n0-1; boundary VM(6)
      if (pf) STAGE_A1(t + 2, 0)
      BAR(); PRIO1(); MFMA16(4, 0, pBlo); PRIO0();
      if (pf) VM(6); else VM(0);
      BAR();

      // ph5: read A0(t+1)+Blo(t+1); stage A0(t+2); MFMA m0-3 x n0-1
      READ_A(b1, 0) READ_BLO(b1)
      if (pf) STAGE_A0(t + 2, 0)
      BAR(); PRIO1(); MFMA16(0, 0, pBlo); PRIO0(); BAR();
      // ph6: read Bhi(t+1); stage A0(t+3)+Blo(t+3); MFMA m0-3 x n2-3
      READ_BHI(b1)
      if (pf) { STAGE_A0(t + 3, 1) STAGE_B(t + 3, 1, 0) }
      BAR(); PRIO1(); MFMA16(0, 2, pBhi); PRIO0(); BAR();
      // ph7: read A1(t+1); stage Bhi(t+3); MFMA m4-7 x n2-3
      READ_A(b1, 4)
      if (pf) STAGE_B(t + 3, 1, 1)
      BAR(); PRIO1(); MFMA16(4, 2, pBhi); PRIO0(); BAR();
      // ph8: regs only; stage A1(t+3); MFMA m4-7 x n0-1; boundary VM(6)
      if (pf) STAGE_A1(t + 3, 1)
      BAR(); PRIO1(); MFMA16(4, 0, pBlo); PRIO0();
      if (pf) VM(6); else VM(0);
      BAR();
    }
  } else {
    // ---- fused-transpose loop (r14, unchanged) ----
    TLOAD(0)
    if (TMODE == 1) { STAGE_B(0, 0, 0) STAGE_B(0, 0, 1) }
    else            { STAGE_A(0, 0, 0) STAGE_A(0, 0, 1) }
    VM(0);
    TCVT(0)
    LGKMW();
    BAR();
    for (int t = 0; t < nt; ++t) {
      const u16* bb = &lds[t & 1][0];
      const int nxb = (t + 1) & 1;
      const bool pf = (t + 1 < nt);

      if (pf) {
        TLOAD(t + 1)   // 8 dwordx4 (issued first -> oldest in VMEM FIFO)
        if (TMODE == 1) { STAGE_B(t + 1, nxb, 0) STAGE_B(t + 1, nxb, 1) }
        else            { STAGE_A(t + 1, nxb, 0) STAGE_A(t + 1, nxb, 1) }
      }

      READ_A(bb, 0) READ_BLO(bb)
      BAR(); PRIO1(); MFMA16(0, 0, pBlo); PRIO0(); BAR();

      READ_BHI(bb)
      BAR(); PRIO1(); MFMA16(0, 2, pBhi); PRIO0(); BAR();

      READ_A(bb, 4)
      BAR(); PRIO1(); MFMA16(4, 2, pBhi); PRIO0();
      // overlap zone: retire the 8 TLOADs only (2 STAGE DMAs stay in flight),
      // then convert+write t+1's transposed operand while ph4 proceeds.
      if (pf) { VM(2); TCVT(nxb) }
      BAR();

      BAR(); PRIO1(); MFMA16(4, 0, pBlo); PRIO0();
      VM(0);   // 2 DMAs issued a full tile ago -> no stall
      LGKMW(); // TCVT ds_writes visible to other waves
      BAR();
    }
  }
#undef STAGE_A0
#undef STAGE_A1
#undef STAGE_A
#undef STAGE_B
#undef TLOAD
#undef TCVT
#undef READ_A
#undef READ_BLO
#undef READ_BHI
#undef MFMA16
#undef AOFF
#undef BOFF
#undef BAR
#undef VM
#undef LGKMW
#undef PRIO1
#undef PRIO0

  // C/D layout: col = lane&15, row = (lane>>4)*4 + r  [m89-verified]
  const int crow0 = m0 + wr * 128 + (lane >> 4) * 4;
  const int ccol0 = n0 + wc * 64 + (lane & 15);
  if (BF16OUT) {
    u16* C = (u16*)Cv + (long long)z * sCz;
#pragma unroll
    for (int m = 0; m < 8; ++m)
#pragma unroll
      for (int n = 0; n < 4; ++n)
#pragma unroll
        for (int r = 0; r < 4; ++r)
          C[(long long)(crow0 + m * 16 + r) * ldc + ccol0 + n * 16] = f2bf(acc[m][n][r] * scale);
  } else {
    float* C = (float*)Cv + (long long)z * sCz;
#pragma unroll
    for (int m = 0; m < 8; ++m)
#pragma unroll
      for (int n = 0; n < 4; ++n)
#pragma unroll
        for (int r = 0; r < 4; ++r)
          C[(long long)(crow0 + m * 16 + r) * ldc + ccol0 + n * 16] = acc[m][n][r] * scale;
  }
}

__global__ __launch_bounds__(256) void conv_weights(
    const float* __restrict__ a, const float* __restrict__ b, const float* __restrict__ c,
    u16* __restrict__ oa, u16* __restrict__ ob, u16* __restrict__ oc)
{
  const int which = blockIdx.y;
  const float* s = which == 0 ? a : which == 1 ? b : c;
  u16* d = which == 0 ? oa : which == 1 ? ob : oc;
  const int idx = (blockIdx.x * 256 + threadIdx.x) * 4;
  f32x4 v = *(const f32x4*)(s + idx);
  u16x4 o;
#pragma unroll
  for (int j = 0; j < 4; ++j) o[j] = f2bf(v[j]);
  *(u16x4*)(d + idx) = o;
}

// Row t of S'[t,s] (bf16): mask by index (s<=t), max, sum-exp, write P bf16
// IN PLACE (each thread reads only its own 8 elems before writing them).
__global__ __launch_bounds__(256) void col_softmax(const u16* __restrict__ S, u16* __restrict__ P)
{
  const int t = blockIdx.x;
  const long long rowOff = ((long long)blockIdx.y * 2048 + t) * 2048;
  const u16* row = S + rowOff;
  u16* prow = P + rowOff;
  const int tid = threadIdx.x;
  const int i0 = tid * 8;

  u16x8 a = *(const u16x8*)(row + i0);
  float v[8];
#pragma unroll
  for (int j = 0; j < 8; ++j)
    v[j] = (i0 + j <= t) ? bf2f(a[j]) : -1e30f;  // unwritten/masked discarded by index

  float m = v[0];
#pragma unroll
  for (int j = 1; j < 8; ++j) m = fmaxf(m, v[j]);
#pragma unroll
  for (int off = 32; off; off >>= 1) m = fmaxf(m, __shfl_xor(m, off));
  __shared__ float red[4];
  __shared__ float red2[4];
  if ((tid & 63) == 0) red[tid >> 6] = m;
  __syncthreads();
  m = fmaxf(fmaxf(red[0], red[1]), fmaxf(red[2], red[3]));

  float e[8]; float ssum = 0.f;
#pragma unroll
  for (int j = 0; j < 8; ++j) { e[j] = __expf(v[j] - m); ssum += e[j]; }
#pragma unroll
  for (int off = 32; off; off >>= 1) ssum += __shfl_xor(ssum, off);
  if ((tid & 63) == 0) red2[tid >> 6] = ssum;
  __syncthreads();
  ssum = red2[0] + red2[1] + red2[2] + red2[3];
  const float inv = 1.0f / ssum;
  u16x8 o;
#pragma unroll
  for (int j = 0; j < 8; ++j) o[j] = f2bf(e[j] * inv);
  *(u16x8*)(prow + i0) = o;
}

extern "C" void kernel_launch(void* const* d_in, const int* in_sizes, int n_in,
                              void* d_out, int out_size, void* d_ws, size_t ws_size,
                              hipStream_t stream)
{
  const float* Q  = (const float*)d_in[0];
  const float* K  = (const float*)d_in[1];
  const float* V  = (const float*)d_in[2];
  const float* WQ = (const float*)d_in[3];
  const float* WK = (const float*)d_in[4];
  const float* WV = (const float*)d_in[5];
  float* out = (float*)d_out;

  const size_t MB = 1ull << 20;
  char* w = (char*)d_ws;
  if (ws_size < 326 * MB) {
    fprintf(stderr, "kernel_launch: workspace too small (%zu B, need >= %zu B)\n",
            ws_size, (size_t)(326 * MB));
    return;
  }

  // ws layout (MB): [0,6) weights bf16 | [6,70) Qd_t | [70,134) Kd_t |
  // [134,198) Vd | [198,326) S bf16 all 16 batches (in-place softmax, no P).
  u16* wq  = (u16*)(w + 0 * MB);
  u16* wk  = (u16*)(w + 2 * MB);
  u16* wv  = (u16*)(w + 4 * MB);
  u16* qdt = (u16*)(w + 6 * MB);
  u16* kdt = (u16*)(w + 70 * MB);
  u16* vd  = (u16*)(w + 134 * MB);
  u16* S   = (u16*)(w + 198 * MB);

  conv_weights<<<dim3(1024, 3), 256, 0, stream>>>(WQ, WK, WV, wq, wk, wv);

  // Projections with FUSED transpose+cvt (no conv_transpose pass):
  // Qd_t/Kd_t (b*2048+s, o): TMODE=1 (A = trans(Q/K) from fp32), B = weights.
  gemm_bt<true, true, false, false, false, 1><<<dim3(4, 128, 1), 512, 0, stream>>>(
      wq, wq, Q, qdt, 1024, 0, 1024, 1024, 0, 0, 0, 1.0f);
  gemm_bt<true, true, false, false, false, 1><<<dim3(4, 128, 1), 512, 0, stream>>>(
      wk, wk, K, kdt, 1024, 0, 1024, 1024, 0, 0, 0, 1.0f);
  // Vd (o, s) per batch: TMODE=2 (B = trans(V) from fp32), A = wv.
  gemm_bt<true, true, false, false, false, 2><<<dim3(8, 4, 16), 512, 0, stream>>>(
      wv, wv, V, vd, 1024, 1024, 0, 2048,
      0, 0, (long long)1024 * 2048, 1.0f);

  // S'[t,s] = Kd_t[t,:]·Qd_t[s,:]/32 — compact triangular grid, 36 tiles/z
  // x 16 z = 576 blocks, chunked XCD swizzle (one batch pair per XCD).
  gemm_bt<true, true, true, false, false, 0><<<dim3(36, 1, 16), 512, 0, stream>>>(
      kdt, qdt, nullptr, S, 1024, 1024, 1024, 2048,
      (long long)2048 * 1024, (long long)2048 * 1024, (long long)2048 * 2048, 0.03125f);
  // row-softmax over s (masked by index), IN PLACE
  col_softmax<<<dim3(2048, 16), 256, 0, stream>>>(S, S);
  // out[o,t] = sum_s Vd[o,s] P[t,s] — single dispatch, causal K-limit,
  // tb descending on slowest axis -> LPT balance.
  gemm_bt<false, false, false, true, true, 0><<<dim3(16, 4, 8), 512, 0, stream>>>(
      vd, S, nullptr, out, 2048, 2048, 2048, 2048,
      (long long)1024 * 2048, (long long)2048 * 2048, (long long)1024 * 2048, 1.0f);
}